// Round 6
// baseline (477.700 us; speedup 1.0000x reference)
//
#include <hip/hip_runtime.h>
#include <math.h>

#define Bb 8
#define Ll 1024
#define Dd 256
#define Ee 8
#define Hh 1024
#define LMAXc 512
#define NTOK (Bb*Dd)   // 2048
#define LPAD 1032      // 4 + 1024 + 4 padded token rows per batch

typedef short bf16x8 __attribute__((ext_vector_type(8)));
typedef float f32x4 __attribute__((ext_vector_type(4)));
typedef unsigned short u16x8 __attribute__((ext_vector_type(8)));

__device__ __forceinline__ float gelu_f(float x) {
    return 0.5f * x * (1.0f + erff(x * 0.70710678118654752440f));
}
__device__ __forceinline__ unsigned short f2b(float x) {          // RTN fp32->bf16
    unsigned int u = __float_as_uint(x);
    return (unsigned short)((u + 0x7fffu + ((u >> 16) & 1u)) >> 16);
}
__device__ __forceinline__ float b2f(unsigned short h) {
    return __uint_as_float(((unsigned int)h) << 16);
}
__device__ __forceinline__ void gl_lds16(const void* g, void* l) {
    __builtin_amdgcn_global_load_lds((const __attribute__((address_space(1))) unsigned int*)g,
                                     (__attribute__((address_space(3))) unsigned int*)l, 16, 0, 0);
}

// ---------------- weight pre-split: fp32 -> bf16 hi/lo planes (x4 vectorized) -------------
__global__ __launch_bounds__(256) void split_w4(const float* __restrict__ src,
                                                unsigned short* __restrict__ hi,
                                                unsigned short* __restrict__ lo, int n4) {
    int idx = blockIdx.x * 256 + threadIdx.x;
    if (idx >= n4) return;
    float4 v = ((const float4*)src)[idx];
    ushort2 h01, h23, l01, l23;
    unsigned short h;
    h = f2b(v.x); h01.x = h; l01.x = f2b(v.x - b2f(h));
    h = f2b(v.y); h01.y = h; l01.y = f2b(v.y - b2f(h));
    h = f2b(v.z); h23.x = h; l23.x = f2b(v.z - b2f(h));
    h = f2b(v.w); h23.y = h; l23.y = f2b(v.w - b2f(h));
    ((ushort2*)hi)[idx * 2] = h01; ((ushort2*)hi)[idx * 2 + 1] = h23;
    ((ushort2*)lo)[idx * 2] = l01; ((ushort2*)lo)[idx * 2 + 1] = l23;
}

// ---- pad+split x: [B][L][D] fp32 -> [B][LPAD][D] bf16 hi/lo (pad rows pre-zeroed) ----
__global__ __launch_bounds__(256) void pad_split_x(const float* __restrict__ x,
                                                   unsigned short* __restrict__ xhi,
                                                   unsigned short* __restrict__ xlo) {
    int idx = blockIdx.x * 256 + threadIdx.x;      // over B*L*D/4 = 524288
    int d4 = idx & 63;
    int l  = (idx >> 6) & 1023;
    int b  = idx >> 16;
    float4 v = ((const float4*)x)[idx];
    size_t o = ((size_t)(b * LPAD + 4 + l) * Dd + d4 * 4) >> 1;   // ushort2 index
    ushort2 h01, h23, l01, l23;
    unsigned short h;
    h = f2b(v.x); h01.x = h; l01.x = f2b(v.x - b2f(h));
    h = f2b(v.y); h01.y = h; l01.y = f2b(v.y - b2f(h));
    h = f2b(v.z); h23.x = h; l23.x = f2b(v.z - b2f(h));
    h = f2b(v.w); h23.y = h; l23.y = f2b(v.w - b2f(h));
    ((ushort2*)xhi)[o] = h01; ((ushort2*)xhi)[o + 1] = h23;
    ((ushort2*)xlo)[o] = l01; ((ushort2*)xlo)[o + 1] = l23;
}

// ---- conv weights [3][D][D][3] -> split planes [layer][k][o][i] ----
__global__ __launch_bounds__(256) void repack_split_conv_w(const float* __restrict__ cw,
                                                           unsigned short* __restrict__ whi,
                                                           unsigned short* __restrict__ wlo) {
    int idx = blockIdx.x * 256 + threadIdx.x;      // 3*3*256*256 = 589824 exact
    int i = idx & (Dd - 1);
    int o = (idx >> 8) & (Dd - 1);
    int lk = idx >> 16;
    int layer = lk / 3;
    int k = lk % 3;
    float v = cw[(((size_t)layer * Dd + o) * Dd + i) * 3 + k];
    unsigned short h = f2b(v);
    whi[idx] = h;
    wlo[idx] = f2b(v - b2f(h));
}

// ============================================================================
// conv_mfma: dilated causal-'same' conv as MFMA NT-GEMM over 3 shifted taps.
// 3-pass split-bf16 (router precision). 64x64 tile, 4 waves (2x2 of 32x32).
// MODE 0: out = gelu(acc+bias) -> padded hi/lo planes [B][LPAD][D]
// MODE 1: out = gelu(acc+bias) -> fp32 [B][L][D]
// ============================================================================
template<int MODE>
__global__ __launch_bounds__(256, 2) void conv_mfma(
    const unsigned short* __restrict__ inhi, const unsigned short* __restrict__ inlo, // [B][LPAD][D]
    const unsigned short* __restrict__ whiL, const unsigned short* __restrict__ wloL, // [3][D][D] (k,o,i)
    const float* __restrict__ bias,
    unsigned short* __restrict__ outhi, unsigned short* __restrict__ outlo,
    float* __restrict__ outf, int dil)
{
    __shared__ char smem[16384];   // Ahi 4K | Alo 4K | Bhi 4K | Blo 4K
    char* sAhi = smem;
    char* sAlo = smem + 4096;
    char* sBhi = smem + 8192;
    char* sBlo = smem + 12288;

    const int t = threadIdx.x;
    const int lane = t & 63, w = t >> 6;
    const int r16 = lane & 15, quad = lane >> 4;
    const int wr = w >> 1, wc = w & 1;
    const int row0 = blockIdx.x * 64;            // token rows (64 | 1024 -> same b)
    const int col0 = blockIdx.y * 64;            // out channels
    const int b = row0 >> 10, l0 = row0 & 1023;

    int aoff[2], boff[2];
    #pragma unroll
    for (int i = 0; i < 2; ++i) {
        int ra = wr * 32 + i * 16 + r16;
        aoff[i] = ra * 64 + ((quad ^ ((ra >> 1) & 3)) << 4);
        int rb = wc * 32 + i * 16 + r16;
        boff[i] = rb * 64 + ((quad ^ ((rb >> 1) & 3)) << 4);
    }
    const int rs = t >> 2, ce = ((t & 3) ^ ((rs >> 1) & 3)) << 3;
    const unsigned short* gAhi = inhi + (size_t)(b * LPAD + 4 + l0 + rs) * Dd + ce;
    const unsigned short* gAlo = inlo + (size_t)(b * LPAD + 4 + l0 + rs) * Dd + ce;

    f32x4 acc[2][2];
    const f32x4 zero4 = {0.f, 0.f, 0.f, 0.f};
    #pragma unroll
    for (int i = 0; i < 2; ++i)
        #pragma unroll
        for (int j = 0; j < 2; ++j) acc[i][j] = zero4;

    for (int tap = 0; tap < 3; ++tap) {
        const int sh = (tap - 1) * dil;
        const unsigned short* pAhi = gAhi + sh * Dd;
        const unsigned short* pAlo = gAlo + sh * Dd;
        const unsigned short* gBhi = whiL + ((size_t)tap * Dd + col0 + rs) * Dd + ce;
        const unsigned short* gBlo = wloL + ((size_t)tap * Dd + col0 + rs) * Dd + ce;
        for (int kb = 0; kb < Dd; kb += 32) {
            gl_lds16(pAhi + kb, sAhi + (w << 10));
            gl_lds16(pAlo + kb, sAlo + (w << 10));
            gl_lds16(gBhi + kb, sBhi + (w << 10));
            gl_lds16(gBlo + kb, sBlo + (w << 10));
            __syncthreads();
            bf16x8 ah[2], al[2], bh[2], bl[2];
            #pragma unroll
            for (int i = 0; i < 2; ++i) {
                ah[i] = *(const bf16x8*)(sAhi + aoff[i]);
                al[i] = *(const bf16x8*)(sAlo + aoff[i]);
                bh[i] = *(const bf16x8*)(sBhi + boff[i]);
                bl[i] = *(const bf16x8*)(sBlo + boff[i]);
            }
            #pragma unroll
            for (int mi = 0; mi < 2; ++mi)
                #pragma unroll
                for (int ni = 0; ni < 2; ++ni) {
                    acc[mi][ni] = __builtin_amdgcn_mfma_f32_16x16x32_bf16(ah[mi], bh[ni], acc[mi][ni], 0, 0, 0);
                    acc[mi][ni] = __builtin_amdgcn_mfma_f32_16x16x32_bf16(ah[mi], bl[ni], acc[mi][ni], 0, 0, 0);
                    acc[mi][ni] = __builtin_amdgcn_mfma_f32_16x16x32_bf16(al[mi], bh[ni], acc[mi][ni], 0, 0, 0);
                }
            __syncthreads();
        }
    }

    int cc[2]; float bv[2];
    #pragma unroll
    for (int ni = 0; ni < 2; ++ni) {
        cc[ni] = col0 + wc * 32 + ni * 16 + r16;
        bv[ni] = bias[cc[ni]];
    }
    #pragma unroll
    for (int mi = 0; mi < 2; ++mi) {
        int lb = l0 + wr * 32 + mi * 16 + quad * 4;
        #pragma unroll
        for (int reg = 0; reg < 4; ++reg) {
            int l = lb + reg;
            #pragma unroll
            for (int ni = 0; ni < 2; ++ni) {
                float v = gelu_f(acc[mi][ni][reg] + bv[ni]);
                if (MODE == 0) {
                    size_t o = (size_t)(b * LPAD + 4 + l) * Dd + cc[ni];
                    unsigned short h = f2b(v);
                    outhi[o] = h;
                    outlo[o] = f2b(v - b2f(h));
                } else {
                    outf[(size_t)(b * Ll + l) * Dd + cc[ni]] = v;
                }
            }
        }
    }
}

// ============================================================================
// Sparse expert GEMM: 2-pass split-bf16 (A plain bf16, B hi/lo planes).
// 128x128 tile, 4 waves, 16x16x32 MFMA, BK=32, swizzled LDS, gl_lds staging.
// Only tiles with row0 < cnt[e] do work (top-2 routing => ~cnt/128 tiles).
// GATHER=1: A rows gathered via list (per-lane global addr is legal for
//           global_load_lds; LDS dest stays lane-linear). Pad rows clamp to
//           cnt-1 (real finite values).
// MODE 0: C[e][i compact] = gelu(acc+bias) -> bf16.
// MODE 1: scatter-combine atomicAdd(out[tok], g*(acc+bias)), guard i<cnt.
// ============================================================================
template<int MODE, int GATHER>
__global__ __launch_bounds__(256, 2) void gemm_sp(
    const unsigned short* __restrict__ AG,
    const unsigned short* __restrict__ BhiG, const unsigned short* __restrict__ BloG,
    const float* __restrict__ biasG, const float* __restrict__ gates,
    const int* __restrict__ cntG, const int* __restrict__ listG,
    unsigned short* __restrict__ Cout, float* __restrict__ outf,
    int M, int N, int K)
{
    const int e = blockIdx.z;
    const int cn = cntG[e];
    const int row0 = blockIdx.x * 128;
    if (row0 >= cn) return;                       // uniform early-exit (before barriers)

    __shared__ char smem[24576];
    char* sA   = smem;
    char* sBhi = smem + 8192;
    char* sBlo = smem + 16384;

    const unsigned short* Bhi = BhiG + (size_t)e * N * K;
    const unsigned short* Blo = BloG + (size_t)e * N * K;
    const float* bias = biasG + (size_t)e * N;

    const int t = threadIdx.x;
    const int lane = t & 63, w = t >> 6;
    const int r16 = lane & 15, quad = lane >> 4;
    const int wr = w >> 1, wc = w & 1;
    const int col0 = blockIdx.y * 128;

    int aoff[4], boff[4];
    #pragma unroll
    for (int i = 0; i < 4; ++i) {
        int ra = wr * 64 + i * 16 + r16;
        aoff[i] = ra * 64 + ((quad ^ ((ra >> 1) & 3)) << 4);
        int rb = wc * 64 + i * 16 + r16;
        boff[i] = rb * 64 + ((quad ^ ((rb >> 1) & 3)) << 4);
    }
    const int s0 = t, s1 = t + 256;
    const int r0s = s0 >> 2, c0s = ((s0 & 3) ^ ((r0s >> 1) & 3)) << 3;
    const int r1s = s1 >> 2, c1s = ((s1 & 3) ^ ((r1s >> 1) & 3)) << 3;
    int ri0 = row0 + r0s; if (ri0 > cn - 1) ri0 = cn - 1;
    int ri1 = row0 + r1s; if (ri1 > cn - 1) ri1 = cn - 1;
    const int ar0 = GATHER ? listG[e * NTOK + ri0] : ri0;
    const int ar1 = GATHER ? listG[e * NTOK + ri1] : ri1;
    const unsigned short* gA0 = AG + ((size_t)e * M + ar0) * K + c0s;
    const unsigned short* gA1 = AG + ((size_t)e * M + ar1) * K + c1s;
    const unsigned short* gBhi0 = Bhi + (size_t)(col0 + r0s) * K + c0s;
    const unsigned short* gBhi1 = Bhi + (size_t)(col0 + r1s) * K + c1s;
    const unsigned short* gBlo0 = Blo + (size_t)(col0 + r0s) * K + c0s;
    const unsigned short* gBlo1 = Blo + (size_t)(col0 + r1s) * K + c1s;

    f32x4 acc[4][4];
    const f32x4 zero4 = {0.f, 0.f, 0.f, 0.f};
    #pragma unroll
    for (int i = 0; i < 4; ++i)
        #pragma unroll
        for (int j = 0; j < 4; ++j) acc[i][j] = zero4;

    for (int k0 = 0; k0 < K; k0 += 32) {
        gl_lds16(gA0 + k0, sA + (w << 10));
        gl_lds16(gA1 + k0, sA + 4096 + (w << 10));
        gl_lds16(gBhi0 + k0, sBhi + (w << 10));
        gl_lds16(gBhi1 + k0, sBhi + 4096 + (w << 10));
        gl_lds16(gBlo0 + k0, sBlo + (w << 10));
        gl_lds16(gBlo1 + k0, sBlo + 4096 + (w << 10));
        __syncthreads();
        bf16x8 ah[4], bh[4], bl[4];
        #pragma unroll
        for (int i = 0; i < 4; ++i) {
            ah[i] = *(const bf16x8*)(sA + aoff[i]);
            bh[i] = *(const bf16x8*)(sBhi + boff[i]);
            bl[i] = *(const bf16x8*)(sBlo + boff[i]);
        }
        #pragma unroll
        for (int mi = 0; mi < 4; ++mi)
            #pragma unroll
            for (int ni = 0; ni < 4; ++ni) {
                acc[mi][ni] = __builtin_amdgcn_mfma_f32_16x16x32_bf16(ah[mi], bh[ni], acc[mi][ni], 0, 0, 0);
                acc[mi][ni] = __builtin_amdgcn_mfma_f32_16x16x32_bf16(ah[mi], bl[ni], acc[mi][ni], 0, 0, 0);
            }
        __syncthreads();
    }

    int cc[4]; float bv[4];
    #pragma unroll
    for (int ni = 0; ni < 4; ++ni) {
        cc[ni] = col0 + wc * 64 + ni * 16 + r16;
        bv[ni] = bias[cc[ni]];
    }
    if (MODE == 0) {
        unsigned short* CE = Cout + (size_t)e * M * N;
        #pragma unroll
        for (int mi = 0; mi < 4; ++mi) {
            int rb = row0 + wr * 64 + mi * 16 + quad * 4;
            #pragma unroll
            for (int reg = 0; reg < 4; ++reg) {
                size_t roff = (size_t)(rb + reg) * N;
                #pragma unroll
                for (int ni = 0; ni < 4; ++ni)
                    CE[roff + cc[ni]] = f2b(gelu_f(acc[mi][ni][reg] + bv[ni]));
            }
        }
    } else {
        #pragma unroll
        for (int mi = 0; mi < 4; ++mi) {
            int rb = row0 + wr * 64 + mi * 16 + quad * 4;
            #pragma unroll
            for (int reg = 0; reg < 4; ++reg) {
                int i = rb + reg;
                if (i < cn) {                               // valid compact row only
                    int tok = listG[e * NTOK + i];
                    float g = gates[(size_t)tok * Ee + e];
                    size_t roff = (size_t)tok * N;
                    #pragma unroll
                    for (int ni = 0; ni < 4; ++ni)
                        atomicAdd(&outf[roff + cc[ni]], g * (acc[mi][ni][reg] + bv[ni]));
                }
            }
        }
    }
}

// ============================ router tail + downsample ==============================

__global__ __launch_bounds__(256) void logits_accum(const float* __restrict__ h,
                                                    const float* __restrict__ fl_w,
                                                    float* __restrict__ logits) {
    int b = blockIdx.x;
    int chunk = blockIdx.y;
    __shared__ float wsm[Ee][128];
    for (int i = threadIdx.x; i < Ee * 128; i += 256) {
        int e = i >> 7, l = i & 127;
        wsm[e][l] = fl_w[e * Ll + chunk * 128 + l];
    }
    __syncthreads();
    int d = threadIdx.x;
    float acc[Ee] = {};
    for (int l = 0; l < 128; ++l) {
        float v = h[((size_t)b * Ll + chunk * 128 + l) * Dd + d];
        #pragma unroll
        for (int e = 0; e < Ee; ++e) acc[e] += v * wsm[e][l];
    }
    int tok = b * Dd + d;
    #pragma unroll
    for (int e = 0; e < Ee; ++e) atomicAdd(&logits[tok * Ee + e], acc[e]);
}

// sigmoid -> softmax -> top2 -> gates + per-expert token lists (sparse dispatch)
__global__ __launch_bounds__(256) void gates_final(const float* __restrict__ logits,
                                                   const float* __restrict__ fl_b,
                                                   float* __restrict__ gates,
                                                   int* __restrict__ cnt,
                                                   int* __restrict__ list) {
    int tok = blockIdx.x * 256 + threadIdx.x;
    if (tok >= NTOK) return;
    float s[Ee];
    #pragma unroll
    for (int e = 0; e < Ee; ++e) {
        float z = logits[tok * Ee + e] + fl_b[e];
        s[e] = 1.0f / (1.0f + expf(-z));
    }
    float mx = s[0];
    #pragma unroll
    for (int e = 1; e < Ee; ++e) mx = fmaxf(mx, s[e]);
    float p[Ee];
    #pragma unroll
    for (int e = 0; e < Ee; ++e) p[e] = expf(s[e] - mx);
    int i1 = 0;
    #pragma unroll
    for (int e = 1; e < Ee; ++e) if (p[e] > p[i1]) i1 = e;
    int i2 = (i1 == 0) ? 1 : 0;
    #pragma unroll
    for (int e = 0; e < Ee; ++e) {
        if (e == i1 || e == i2) continue;
        if (p[e] > p[i2]) i2 = e;
    }
    float inv = 1.0f / (p[i1] + p[i2]);
    #pragma unroll
    for (int e = 0; e < Ee; ++e) gates[tok * Ee + e] = 0.0f;
    gates[tok * Ee + i1] = p[i1] * inv;
    gates[tok * Ee + i2] = p[i2] * inv;
    int p1 = atomicAdd(&cnt[i1], 1);
    list[i1 * NTOK + p1] = tok;
    int p2 = atomicAdd(&cnt[i2], 1);
    list[i2 * NTOK + p2] = tok;
}

// downsample v3: single bf16 plane, valid region only (xe pad cols multiply
// zero w1 cols -> any finite value OK). 8 j/thread, r-outer for load ILP.
__global__ __launch_bounds__(256) void downsample_v3(const float* __restrict__ x,
                                                     unsigned short* __restrict__ xe) {
    int e = blockIdx.z;
    int f = e + 2;
    int Li = Ll / f;
    int j0 = blockIdx.x * 8;
    if (j0 >= Li) return;
    int b = blockIdx.y;
    int d = threadIdx.x;
    float invf = 1.0f / (float)f;
    int lim = Li - 1;
    float v[8] = {};
    for (int r = 0; r < f; ++r) {
        #pragma unroll
        for (int jj = 0; jj < 8; ++jj) {
            int j = j0 + jj; if (j > lim) j = lim;        // clamp addr; masked at write
            v[jj] += x[((size_t)(b * Ll + j * f + r)) * Dd + d];
        }
    }
    size_t obase = ((size_t)(e * NTOK + b * 256 + d)) * LMAXc + j0;
    if (j0 + 8 <= Li) {
        u16x8 hv;
        #pragma unroll
        for (int q = 0; q < 8; ++q) hv[q] = (short)f2b(v[q] * invf);
        *(u16x8*)(xe + obase) = hv;
    } else {
        for (int jj = 0; jj < Li - j0; ++jj)
            xe[obase + jj] = f2b(v[jj] * invf);
    }
}

__global__ __launch_bounds__(256) void transpose_out(const float* __restrict__ outacc,
                                                     float* __restrict__ out) {
    __shared__ float tile[32][33];
    int b = blockIdx.z;
    int d0 = blockIdx.x * 32;
    int o0 = blockIdx.y * 32;
    int tx = threadIdx.x & 31, ty = threadIdx.x >> 5;
    for (int i = 0; i < 32; i += 8)
        tile[ty + i][tx] = outacc[((size_t)b * Dd + d0 + ty + i) * Hh + o0 + tx];
    __syncthreads();
    for (int i = 0; i < 32; i += 8)
        out[((size_t)b * Hh + o0 + ty + i) * Dd + d0 + tx] = tile[tx][ty + i];
}

extern "C" void kernel_launch(void* const* d_in, const int* in_sizes, int n_in,
                              void* d_out, int out_size, void* d_ws, size_t ws_size,
                              hipStream_t stream) {
    const float* x       = (const float*)d_in[0];
    const float* conv_w  = (const float*)d_in[1];
    const float* conv_b  = (const float*)d_in[2];
    const float* fl_w    = (const float*)d_in[3];
    const float* fl_b    = (const float*)d_in[4];
    const float* w1      = (const float*)d_in[5];
    const float* b1      = (const float*)d_in[6];
    const float* w2      = (const float*)d_in[7];
    const float* b2      = (const float*)d_in[8];
    const float* w3      = (const float*)d_in[9];
    const float* b3      = (const float*)d_in[10];
    float* out = (float*)d_out;

    char* ws = (char*)d_ws;
    // Workspace (peak ~151.2 MB). h1 region (0..33.5MB) is overlaid by the conv
    // buffers until gemm1, then by outacc after gemm2:
    //   conv region (under h1): xphi/xplo/cphi/cplo/wchi/wclo/hL (as R5)
    //   h1c   @ 0            33,554,432 bf16 compact per expert
    //   h2c   @ 33,554,432   33,554,432 bf16 compact
    //   xe    @ 67,108,864   16,777,216 bf16 -> w3hi after gemm1
    //   w3lo  @ 83,886,080   16,777,216
    //   w1hi  @ 100,663,296   8,388,608
    //   w1lo  @ 109,051,904   8,388,608
    //   w2hi  @ 117,440,512  16,777,216
    //   w2lo  @ 134,217,728  16,777,216
    //   logits@ 150,994,944      65,536
    //   gates @ 151,060,480      65,536
    //   list  @ 151,126,016      65,536  [E][NTOK] int
    //   cnt   @ 151,191,552          32  [E] int
    unsigned short* xphi = (unsigned short*)(ws);
    unsigned short* xplo = (unsigned short*)(ws + 4227072);
    unsigned short* cphi = (unsigned short*)(ws + 8454144);
    unsigned short* cplo = (unsigned short*)(ws + 12681216);
    unsigned short* wchi = (unsigned short*)(ws + 16908288);
    unsigned short* wclo = (unsigned short*)(ws + 18087936);
    float* hL            = (float*)(ws + 19267584);
    unsigned short* h1   = (unsigned short*)(ws);
    unsigned short* h2   = (unsigned short*)(ws + 33554432);
    unsigned short* xe   = (unsigned short*)(ws + 67108864);
    unsigned short* w3hi = (unsigned short*)(ws + 67108864);
    unsigned short* w3lo = (unsigned short*)(ws + 83886080);
    unsigned short* w1hi = (unsigned short*)(ws + 100663296);
    unsigned short* w1lo = (unsigned short*)(ws + 109051904);
    unsigned short* w2hi = (unsigned short*)(ws + 117440512);
    unsigned short* w2lo = (unsigned short*)(ws + 134217728);
    float* logits = (float*)(ws + 150994944);
    float* gates  = (float*)(ws + 151060480);
    int*   list   = (int*)(ws + 151126016);
    int*   cnt    = (int*)(ws + 151191552);
    float* outacc = (float*)(ws);

    hipMemsetAsync(logits, 0, NTOK * Ee * sizeof(float), stream);
    hipMemsetAsync(cnt, 0, Ee * sizeof(int), stream);
    // zero padded conv buffers (pad rows must be 0; interiors overwritten)
    hipMemsetAsync(ws, 0, 16908288, stream);

    pad_split_x<<<2048, 256, 0, stream>>>(x, xphi, xplo);
    repack_split_conv_w<<<2304, 256, 0, stream>>>(conv_w, wchi, wclo);
    split_w4<<<4096, 256, 0, stream>>>(w1, w1hi, w1lo, Ee * Hh * LMAXc / 4);
    split_w4<<<8192, 256, 0, stream>>>(w2, w2hi, w2lo, Ee * Hh * Hh / 4);

    // Router convs on MFMA (3-pass split — ~1e-7 relative, safe for discrete top-2)
    const int WL = 3 * Dd * Dd;
    conv_mfma<0><<<dim3(Bb * Ll / 64, Dd / 64), 256, 0, stream>>>(
        xphi, xplo, wchi + 0 * WL, wclo + 0 * WL, conv_b + 0 * Dd, cphi, cplo, nullptr, 1);
    conv_mfma<0><<<dim3(Bb * Ll / 64, Dd / 64), 256, 0, stream>>>(
        cphi, cplo, wchi + 1 * WL, wclo + 1 * WL, conv_b + 1 * Dd, xphi, xplo, nullptr, 2);
    conv_mfma<1><<<dim3(Bb * Ll / 64, Dd / 64), 256, 0, stream>>>(
        xphi, xplo, wchi + 2 * WL, wclo + 2 * WL, conv_b + 2 * Dd, nullptr, nullptr, hL, 4);

    logits_accum<<<dim3(Bb, 8), 256, 0, stream>>>(hL, fl_w, logits);
    gates_final<<<NTOK / 256, 256, 0, stream>>>(logits, fl_b, gates, cnt, list);

    downsample_v3<<<dim3(64, Bb, Ee), 256, 0, stream>>>(x, xe);

    // GEMM1 sparse (gathered A from xe): writes h1 compact over the dead conv region
    gemm_sp<0, 1><<<dim3(NTOK / 128, Hh / 128, Ee), 256, 0, stream>>>(
        xe, w1hi, w1lo, b1, nullptr, cnt, list, h1, nullptr, NTOK, Hh, LMAXc);

    // xe dead: split w3 into its slot
    split_w4<<<8192, 256, 0, stream>>>(w3, w3hi, w3lo, Ee * Hh * Hh / 4);

    // GEMM2 sparse (compact->compact)
    gemm_sp<0, 0><<<dim3(NTOK / 128, Hh / 128, Ee), 256, 0, stream>>>(
        h1, w2hi, w2lo, b2, nullptr, cnt, list, h2, nullptr, NTOK, Hh, Hh);

    // h1 dead: zero outacc in its slot
    hipMemsetAsync(outacc, 0, (size_t)NTOK * Hh * sizeof(float), stream);

    // GEMM3 sparse (compact A, gated scatter-add combine)
    gemm_sp<1, 0><<<dim3(NTOK / 128, Hh / 128, Ee), 256, 0, stream>>>(
        h2, w3hi, w3lo, b3, gates, cnt, list, nullptr, outacc, NTOK, Hh, Hh);

    transpose_out<<<dim3(Dd / 32, Hh / 32, Bb), 256, 0, stream>>>(outacc, out);
}

// Round 7
// 415.994 us; speedup vs baseline: 1.1483x; 1.1483x over previous
//
#include <hip/hip_runtime.h>
#include <math.h>

#define Bb 8
#define Ll 1024
#define Dd 256
#define Ee 8
#define Hh 1024
#define LMAXc 512
#define NTOK (Bb*Dd)   // 2048
#define LPAD 1032      // 4 + 1024 + 4 padded token rows per batch
#define MAXTILES 72    // worst-case sum_e ceil(cnt[e]/64): 4096/64 + 7

typedef short bf16x8 __attribute__((ext_vector_type(8)));
typedef float f32x4 __attribute__((ext_vector_type(4)));
typedef unsigned short u16x8 __attribute__((ext_vector_type(8)));

__device__ __forceinline__ float gelu_f(float x) {
    return 0.5f * x * (1.0f + erff(x * 0.70710678118654752440f));
}
__device__ __forceinline__ unsigned short f2b(float x) {          // RTN fp32->bf16
    unsigned int u = __float_as_uint(x);
    return (unsigned short)((u + 0x7fffu + ((u >> 16) & 1u)) >> 16);
}
__device__ __forceinline__ float b2f(unsigned short h) {
    return __uint_as_float(((unsigned int)h) << 16);
}
__device__ __forceinline__ void gl_lds16(const void* g, void* l) {
    __builtin_amdgcn_global_load_lds((const __attribute__((address_space(1))) unsigned int*)g,
                                     (__attribute__((address_space(3))) unsigned int*)l, 16, 0, 0);
}
__device__ __forceinline__ void split_one4(const float* __restrict__ src,
                                           unsigned short* __restrict__ hi,
                                           unsigned short* __restrict__ lo, int idx) {
    float4 v = ((const float4*)src)[idx];
    ushort2 h01, h23, l01, l23;
    unsigned short h;
    h = f2b(v.x); h01.x = h; l01.x = f2b(v.x - b2f(h));
    h = f2b(v.y); h01.y = h; l01.y = f2b(v.y - b2f(h));
    h = f2b(v.z); h23.x = h; l23.x = f2b(v.z - b2f(h));
    h = f2b(v.w); h23.y = h; l23.y = f2b(v.w - b2f(h));
    ((ushort2*)hi)[idx * 2] = h01; ((ushort2*)hi)[idx * 2 + 1] = h23;
    ((ushort2*)lo)[idx * 2] = l01; ((ushort2*)lo)[idx * 2 + 1] = l23;
}

// ---------------- standalone splitter (w3, launched after gemm1) ----------------
__global__ __launch_bounds__(256) void split_w4(const float* __restrict__ src,
                                                unsigned short* __restrict__ hi,
                                                unsigned short* __restrict__ lo, int n4) {
    int idx = blockIdx.x * 256 + threadIdx.x;
    if (idx >= n4) return;
    split_one4(src, hi, lo, idx);
}

// ============================================================================
// prep_all: fused prep (saves 3 launches)
//   [0,2048)    : pad+split x -> [B][LPAD][D] bf16 hi/lo planes (interior)
//   [2048,4352) : conv weights [3][D][D][3] -> split planes [layer][k][o][i]
//   [4352,8448) : split w1 (n4 = 1,048,576, exact)
//   [8448,16640): split w2 (n4 = 2,097,152, exact)
// ============================================================================
__global__ __launch_bounds__(256) void prep_all(
    const float* __restrict__ x, const float* __restrict__ cw,
    const float* __restrict__ w1, const float* __restrict__ w2,
    unsigned short* __restrict__ xhi, unsigned short* __restrict__ xlo,
    unsigned short* __restrict__ wchi, unsigned short* __restrict__ wclo,
    unsigned short* __restrict__ w1hi, unsigned short* __restrict__ w1lo,
    unsigned short* __restrict__ w2hi, unsigned short* __restrict__ w2lo)
{
    int blk = blockIdx.x;
    int t = threadIdx.x;
    if (blk < 2048) {
        int idx = blk * 256 + t;                   // over B*L*D/4 = 524288
        int d4 = idx & 63;
        int l  = (idx >> 6) & 1023;
        int b  = idx >> 16;
        float4 v = ((const float4*)x)[idx];
        size_t o = ((size_t)(b * LPAD + 4 + l) * Dd + d4 * 4) >> 1;
        ushort2 h01, h23, l01, l23;
        unsigned short h;
        h = f2b(v.x); h01.x = h; l01.x = f2b(v.x - b2f(h));
        h = f2b(v.y); h01.y = h; l01.y = f2b(v.y - b2f(h));
        h = f2b(v.z); h23.x = h; l23.x = f2b(v.z - b2f(h));
        h = f2b(v.w); h23.y = h; l23.y = f2b(v.w - b2f(h));
        ((ushort2*)xhi)[o] = h01; ((ushort2*)xhi)[o + 1] = h23;
        ((ushort2*)xlo)[o] = l01; ((ushort2*)xlo)[o + 1] = l23;
    } else if (blk < 4352) {
        int idx = (blk - 2048) * 256 + t;          // 589824 exact
        int i = idx & (Dd - 1);
        int o = (idx >> 8) & (Dd - 1);
        int lk = idx >> 16;
        int layer = lk / 3;
        int k = lk % 3;
        float v = cw[(((size_t)layer * Dd + o) * Dd + i) * 3 + k];
        unsigned short h = f2b(v);
        wchi[idx] = h;
        wclo[idx] = f2b(v - b2f(h));
    } else if (blk < 8448) {
        split_one4(w1, w1hi, w1lo, (blk - 4352) * 256 + t);
    } else {
        split_one4(w2, w2hi, w2lo, (blk - 8448) * 256 + t);
    }
}

// ============================================================================
// conv_mfma: dilated causal-'same' conv as MFMA NT-GEMM over 3 shifted taps.
// 3-pass split-bf16 (router precision). 64x64 tile, 4 waves (2x2 of 32x32).
// ============================================================================
template<int MODE>
__global__ __launch_bounds__(256, 2) void conv_mfma(
    const unsigned short* __restrict__ inhi, const unsigned short* __restrict__ inlo,
    const unsigned short* __restrict__ whiL, const unsigned short* __restrict__ wloL,
    const float* __restrict__ bias,
    unsigned short* __restrict__ outhi, unsigned short* __restrict__ outlo,
    float* __restrict__ outf, int dil)
{
    __shared__ char smem[16384];
    char* sAhi = smem;
    char* sAlo = smem + 4096;
    char* sBhi = smem + 8192;
    char* sBlo = smem + 12288;

    const int t = threadIdx.x;
    const int lane = t & 63, w = t >> 6;
    const int r16 = lane & 15, quad = lane >> 4;
    const int wr = w >> 1, wc = w & 1;
    const int row0 = blockIdx.x * 64;
    const int col0 = blockIdx.y * 64;
    const int b = row0 >> 10, l0 = row0 & 1023;

    int aoff[2], boff[2];
    #pragma unroll
    for (int i = 0; i < 2; ++i) {
        int ra = wr * 32 + i * 16 + r16;
        aoff[i] = ra * 64 + ((quad ^ ((ra >> 1) & 3)) << 4);
        int rb = wc * 32 + i * 16 + r16;
        boff[i] = rb * 64 + ((quad ^ ((rb >> 1) & 3)) << 4);
    }
    const int rs = t >> 2, ce = ((t & 3) ^ ((rs >> 1) & 3)) << 3;
    const unsigned short* gAhi = inhi + (size_t)(b * LPAD + 4 + l0 + rs) * Dd + ce;
    const unsigned short* gAlo = inlo + (size_t)(b * LPAD + 4 + l0 + rs) * Dd + ce;

    f32x4 acc[2][2];
    const f32x4 zero4 = {0.f, 0.f, 0.f, 0.f};
    #pragma unroll
    for (int i = 0; i < 2; ++i)
        #pragma unroll
        for (int j = 0; j < 2; ++j) acc[i][j] = zero4;

    for (int tap = 0; tap < 3; ++tap) {
        const int sh = (tap - 1) * dil;
        const unsigned short* pAhi = gAhi + sh * Dd;
        const unsigned short* pAlo = gAlo + sh * Dd;
        const unsigned short* gBhi = whiL + ((size_t)tap * Dd + col0 + rs) * Dd + ce;
        const unsigned short* gBlo = wloL + ((size_t)tap * Dd + col0 + rs) * Dd + ce;
        for (int kb = 0; kb < Dd; kb += 32) {
            gl_lds16(pAhi + kb, sAhi + (w << 10));
            gl_lds16(pAlo + kb, sAlo + (w << 10));
            gl_lds16(gBhi + kb, sBhi + (w << 10));
            gl_lds16(gBlo + kb, sBlo + (w << 10));
            __syncthreads();
            bf16x8 ah[2], al[2], bh[2], bl[2];
            #pragma unroll
            for (int i = 0; i < 2; ++i) {
                ah[i] = *(const bf16x8*)(sAhi + aoff[i]);
                al[i] = *(const bf16x8*)(sAlo + aoff[i]);
                bh[i] = *(const bf16x8*)(sBhi + boff[i]);
                bl[i] = *(const bf16x8*)(sBlo + boff[i]);
            }
            #pragma unroll
            for (int mi = 0; mi < 2; ++mi)
                #pragma unroll
                for (int ni = 0; ni < 2; ++ni) {
                    acc[mi][ni] = __builtin_amdgcn_mfma_f32_16x16x32_bf16(ah[mi], bh[ni], acc[mi][ni], 0, 0, 0);
                    acc[mi][ni] = __builtin_amdgcn_mfma_f32_16x16x32_bf16(ah[mi], bl[ni], acc[mi][ni], 0, 0, 0);
                    acc[mi][ni] = __builtin_amdgcn_mfma_f32_16x16x32_bf16(al[mi], bh[ni], acc[mi][ni], 0, 0, 0);
                }
            __syncthreads();
        }
    }

    int cc[2]; float bv[2];
    #pragma unroll
    for (int ni = 0; ni < 2; ++ni) {
        cc[ni] = col0 + wc * 32 + ni * 16 + r16;
        bv[ni] = bias[cc[ni]];
    }
    #pragma unroll
    for (int mi = 0; mi < 2; ++mi) {
        int lb = l0 + wr * 32 + mi * 16 + quad * 4;
        #pragma unroll
        for (int reg = 0; reg < 4; ++reg) {
            int l = lb + reg;
            #pragma unroll
            for (int ni = 0; ni < 2; ++ni) {
                float v = gelu_f(acc[mi][ni][reg] + bv[ni]);
                if (MODE == 0) {
                    size_t o = (size_t)(b * LPAD + 4 + l) * Dd + cc[ni];
                    unsigned short h = f2b(v);
                    outhi[o] = h;
                    outlo[o] = f2b(v - b2f(h));
                } else {
                    outf[(size_t)(b * Ll + l) * Dd + cc[ni]] = v;
                }
            }
        }
    }
}

// ============================================================================
// Sparse expert GEMM v2: balanced flat tile dispatch.
// Tile M=64 x N=128, 4 waves (2x2, wave-tile 32x64), BK=32, 2-pass split-bf16.
// tileTab[i] = (e<<16)|mtile (built by gates_final); blocks >= ntiles exit.
// GATHER=1: A rows gathered via list (per-lane global addr; LDS dest lane-linear).
// MODE 0: C[e][compact] = gelu(acc+bias) -> bf16. MODE 1: gated scatter-add.
// ============================================================================
template<int MODE, int GATHER>
__global__ __launch_bounds__(256, 4) void gemm_sp(
    const unsigned short* __restrict__ AG,
    const unsigned short* __restrict__ BhiG, const unsigned short* __restrict__ BloG,
    const float* __restrict__ biasG, const float* __restrict__ gates,
    const int* __restrict__ cntG, const int* __restrict__ listG,
    const int* __restrict__ tileTab, const int* __restrict__ ntiles,
    unsigned short* __restrict__ Cout, float* __restrict__ outf,
    int M, int N, int K)
{
    if (blockIdx.x >= ntiles[0]) return;          // uniform early-exit
    const int desc = tileTab[blockIdx.x];
    const int e = desc >> 16;
    const int row0 = (desc & 0xffff) * 64;
    const int cn = cntG[e];

    __shared__ char smem[20480];                  // A 4K | Bhi 8K | Blo 8K
    char* sA   = smem;
    char* sBhi = smem + 4096;
    char* sBlo = smem + 12288;

    const unsigned short* Bhi = BhiG + (size_t)e * N * K;
    const unsigned short* Blo = BloG + (size_t)e * N * K;
    const float* bias = biasG + (size_t)e * N;

    const int t = threadIdx.x;
    const int lane = t & 63, w = t >> 6;
    const int r16 = lane & 15, quad = lane >> 4;
    const int wr = w >> 1, wc = w & 1;
    const int col0 = blockIdx.y * 128;

    int aoff[2], boff[4];
    #pragma unroll
    for (int i = 0; i < 2; ++i) {
        int ra = wr * 32 + i * 16 + r16;
        aoff[i] = ra * 64 + ((quad ^ ((ra >> 1) & 3)) << 4);
    }
    #pragma unroll
    for (int j = 0; j < 4; ++j) {
        int rb = wc * 64 + j * 16 + r16;
        boff[j] = rb * 64 + ((quad ^ ((rb >> 1) & 3)) << 4);
    }
    // staging: A 256 slots (slot t); B 512 slots/plane (slots t, t+256)
    const int r0s = t >> 2, c0s = ((t & 3) ^ ((r0s >> 1) & 3)) << 3;
    const int r1s = r0s + 64, c1s = ((t & 3) ^ ((r1s >> 1) & 3)) << 3;
    int ri = row0 + r0s; if (ri > cn - 1) ri = cn - 1;
    const int ar = GATHER ? listG[e * NTOK + ri] : ri;
    const unsigned short* gA  = AG + ((size_t)e * M + ar) * K + c0s;
    const unsigned short* gBhi0 = Bhi + (size_t)(col0 + r0s) * K + c0s;
    const unsigned short* gBhi1 = Bhi + (size_t)(col0 + r1s) * K + c1s;
    const unsigned short* gBlo0 = Blo + (size_t)(col0 + r0s) * K + c0s;
    const unsigned short* gBlo1 = Blo + (size_t)(col0 + r1s) * K + c1s;

    f32x4 acc[2][4];
    const f32x4 zero4 = {0.f, 0.f, 0.f, 0.f};
    #pragma unroll
    for (int i = 0; i < 2; ++i)
        #pragma unroll
        for (int j = 0; j < 4; ++j) acc[i][j] = zero4;

    for (int k0 = 0; k0 < K; k0 += 32) {
        gl_lds16(gA + k0, sA + (w << 10));
        gl_lds16(gBhi0 + k0, sBhi + (w << 10));
        gl_lds16(gBhi1 + k0, sBhi + 4096 + (w << 10));
        gl_lds16(gBlo0 + k0, sBlo + (w << 10));
        gl_lds16(gBlo1 + k0, sBlo + 4096 + (w << 10));
        __syncthreads();
        bf16x8 ah[2], bh[4], bl[4];
        #pragma unroll
        for (int i = 0; i < 2; ++i) ah[i] = *(const bf16x8*)(sA + aoff[i]);
        #pragma unroll
        for (int j = 0; j < 4; ++j) {
            bh[j] = *(const bf16x8*)(sBhi + boff[j]);
            bl[j] = *(const bf16x8*)(sBlo + boff[j]);
        }
        #pragma unroll
        for (int mi = 0; mi < 2; ++mi)
            #pragma unroll
            for (int ni = 0; ni < 4; ++ni) {
                acc[mi][ni] = __builtin_amdgcn_mfma_f32_16x16x32_bf16(ah[mi], bh[ni], acc[mi][ni], 0, 0, 0);
                acc[mi][ni] = __builtin_amdgcn_mfma_f32_16x16x32_bf16(ah[mi], bl[ni], acc[mi][ni], 0, 0, 0);
            }
        __syncthreads();
    }

    int cc[4]; float bv[4];
    #pragma unroll
    for (int ni = 0; ni < 4; ++ni) {
        cc[ni] = col0 + wc * 64 + ni * 16 + r16;
        bv[ni] = bias[cc[ni]];
    }
    if (MODE == 0) {
        unsigned short* CE = Cout + (size_t)e * M * N;
        #pragma unroll
        for (int mi = 0; mi < 2; ++mi) {
            int rb = row0 + wr * 32 + mi * 16 + quad * 4;
            #pragma unroll
            for (int reg = 0; reg < 4; ++reg) {
                size_t roff = (size_t)(rb + reg) * N;
                #pragma unroll
                for (int ni = 0; ni < 4; ++ni)
                    CE[roff + cc[ni]] = f2b(gelu_f(acc[mi][ni][reg] + bv[ni]));
            }
        }
    } else {
        #pragma unroll
        for (int mi = 0; mi < 2; ++mi) {
            int rb = row0 + wr * 32 + mi * 16 + quad * 4;
            #pragma unroll
            for (int reg = 0; reg < 4; ++reg) {
                int i = rb + reg;
                if (i < cn) {
                    int tok = listG[e * NTOK + i];
                    float g = gates[(size_t)tok * Ee + e];
                    size_t roff = (size_t)tok * N;
                    #pragma unroll
                    for (int ni = 0; ni < 4; ++ni)
                        atomicAdd(&outf[roff + cc[ni]], g * (acc[mi][ni][reg] + bv[ni]));
                }
            }
        }
    }
}

// ============================ router tail + downsample ==============================

__global__ __launch_bounds__(256) void logits_accum(const float* __restrict__ h,
                                                    const float* __restrict__ fl_w,
                                                    float* __restrict__ logits) {
    int b = blockIdx.x;
    int chunk = blockIdx.y;
    __shared__ float wsm[Ee][128];
    for (int i = threadIdx.x; i < Ee * 128; i += 256) {
        int e = i >> 7, l = i & 127;
        wsm[e][l] = fl_w[e * Ll + chunk * 128 + l];
    }
    __syncthreads();
    int d = threadIdx.x;
    float acc[Ee] = {};
    for (int l = 0; l < 128; ++l) {
        float v = h[((size_t)b * Ll + chunk * 128 + l) * Dd + d];
        #pragma unroll
        for (int e = 0; e < Ee; ++e) acc[e] += v * wsm[e][l];
    }
    int tok = b * Dd + d;
    #pragma unroll
    for (int e = 0; e < Ee; ++e) atomicAdd(&logits[tok * Ee + e], acc[e]);
}

// sigmoid -> softmax -> top2 -> gates + per-expert lists + balanced tile table.
// ONE block of 1024 threads (2 toks each) so cnt is final before table build.
__global__ __launch_bounds__(1024) void gates_final(const float* __restrict__ logits,
                                                    const float* __restrict__ fl_b,
                                                    float* __restrict__ gates,
                                                    int* __restrict__ cnt,
                                                    int* __restrict__ list,
                                                    int* __restrict__ tileTab,
                                                    int* __restrict__ ntiles) {
    for (int tok = threadIdx.x; tok < NTOK; tok += 1024) {
        float s[Ee];
        #pragma unroll
        for (int e = 0; e < Ee; ++e) {
            float z = logits[tok * Ee + e] + fl_b[e];
            s[e] = 1.0f / (1.0f + expf(-z));
        }
        float mx = s[0];
        #pragma unroll
        for (int e = 1; e < Ee; ++e) mx = fmaxf(mx, s[e]);
        float p[Ee];
        #pragma unroll
        for (int e = 0; e < Ee; ++e) p[e] = expf(s[e] - mx);
        int i1 = 0;
        #pragma unroll
        for (int e = 1; e < Ee; ++e) if (p[e] > p[i1]) i1 = e;
        int i2 = (i1 == 0) ? 1 : 0;
        #pragma unroll
        for (int e = 0; e < Ee; ++e) {
            if (e == i1 || e == i2) continue;
            if (p[e] > p[i2]) i2 = e;
        }
        float inv = 1.0f / (p[i1] + p[i2]);
        #pragma unroll
        for (int e = 0; e < Ee; ++e) gates[tok * Ee + e] = 0.0f;
        gates[tok * Ee + i1] = p[i1] * inv;
        gates[tok * Ee + i2] = p[i2] * inv;
        int p1 = atomicAdd(&cnt[i1], 1);
        list[i1 * NTOK + p1] = tok;
        int p2 = atomicAdd(&cnt[i2], 1);
        list[i2 * NTOK + p2] = tok;
    }
    __syncthreads();
    if (threadIdx.x == 0) {
        int nt = 0;
        for (int e = 0; e < Ee; ++e) {
            int c = atomicAdd(&cnt[e], 0);        // coherent read (atomics bypass L1)
            for (int m = 0; m * 64 < c; ++m) tileTab[nt++] = (e << 16) | m;
        }
        ntiles[0] = nt;
    }
}

// downsample v3: single bf16 plane, valid region only (xe pad cols hit zero
// w1 cols). 8 j/thread, r-outer for load ILP; early-exit past Li.
__global__ __launch_bounds__(256) void downsample_v3(const float* __restrict__ x,
                                                     unsigned short* __restrict__ xe) {
    int e = blockIdx.z;
    int f = e + 2;
    int Li = Ll / f;
    int j0 = blockIdx.x * 8;
    if (j0 >= Li) return;
    int b = blockIdx.y;
    int d = threadIdx.x;
    float invf = 1.0f / (float)f;
    int lim = Li - 1;
    float v[8] = {};
    for (int r = 0; r < f; ++r) {
        #pragma unroll
        for (int jj = 0; jj < 8; ++jj) {
            int j = j0 + jj; if (j > lim) j = lim;
            v[jj] += x[((size_t)(b * Ll + j * f + r)) * Dd + d];
        }
    }
    size_t obase = ((size_t)(e * NTOK + b * 256 + d)) * LMAXc + j0;
    if (j0 + 8 <= Li) {
        u16x8 hv;
        #pragma unroll
        for (int q = 0; q < 8; ++q) hv[q] = (short)f2b(v[q] * invf);
        *(u16x8*)(xe + obase) = hv;
    } else {
        for (int jj = 0; jj < Li - j0; ++jj)
            xe[obase + jj] = f2b(v[jj] * invf);
    }
}

__global__ __launch_bounds__(256) void transpose_out(const float* __restrict__ outacc,
                                                     float* __restrict__ out) {
    __shared__ float tile[32][33];
    int b = blockIdx.z;
    int d0 = blockIdx.x * 32;
    int o0 = blockIdx.y * 32;
    int tx = threadIdx.x & 31, ty = threadIdx.x >> 5;
    for (int i = 0; i < 32; i += 8)
        tile[ty + i][tx] = outacc[((size_t)b * Dd + d0 + ty + i) * Hh + o0 + tx];
    __syncthreads();
    for (int i = 0; i < 32; i += 8)
        out[((size_t)b * Hh + o0 + ty + i) * Dd + d0 + tx] = tile[tx][ty + i];
}

extern "C" void kernel_launch(void* const* d_in, const int* in_sizes, int n_in,
                              void* d_out, int out_size, void* d_ws, size_t ws_size,
                              hipStream_t stream) {
    const float* x       = (const float*)d_in[0];
    const float* conv_w  = (const float*)d_in[1];
    const float* conv_b  = (const float*)d_in[2];
    const float* fl_w    = (const float*)d_in[3];
    const float* fl_b    = (const float*)d_in[4];
    const float* w1      = (const float*)d_in[5];
    const float* b1      = (const float*)d_in[6];
    const float* w2      = (const float*)d_in[7];
    const float* b2      = (const float*)d_in[8];
    const float* w3      = (const float*)d_in[9];
    const float* b3      = (const float*)d_in[10];
    float* out = (float*)d_out;

    char* ws = (char*)d_ws;
    // Workspace (peak ~151.2 MB, proven). h1 region overlaid by conv buffers
    // until gemm1, then by outacc after gemm2:
    //   conv region (under h1): xphi/xplo/cphi/cplo/wchi/wclo/hL
    //   h1c   @ 0            33,554,432 bf16 compact per expert
    //   h2c   @ 33,554,432   33,554,432 bf16 compact
    //   xe    @ 67,108,864   16,777,216 bf16 -> w3hi after gemm1
    //   w3lo  @ 83,886,080   16,777,216
    //   w1hi  @ 100,663,296   8,388,608
    //   w1lo  @ 109,051,904   8,388,608
    //   w2hi  @ 117,440,512  16,777,216
    //   w2lo  @ 134,217,728  16,777,216
    //   logits@ 150,994,944      65,536   \ one memset covers
    //   cnt   @ 151,060,480          32   |  logits+cnt+ntiles
    //   ntiles@ 151,060,512           4  /
    //   tileTab@151,060,544         288
    //   gates @ 151,061,504      65,536
    //   list  @ 151,127,040      65,536
    unsigned short* xphi = (unsigned short*)(ws);
    unsigned short* xplo = (unsigned short*)(ws + 4227072);
    unsigned short* cphi = (unsigned short*)(ws + 8454144);
    unsigned short* cplo = (unsigned short*)(ws + 12681216);
    unsigned short* wchi = (unsigned short*)(ws + 16908288);
    unsigned short* wclo = (unsigned short*)(ws + 18087936);
    float* hL            = (float*)(ws + 19267584);
    unsigned short* h1   = (unsigned short*)(ws);
    unsigned short* h2   = (unsigned short*)(ws + 33554432);
    unsigned short* xe   = (unsigned short*)(ws + 67108864);
    unsigned short* w3hi = (unsigned short*)(ws + 67108864);
    unsigned short* w3lo = (unsigned short*)(ws + 83886080);
    unsigned short* w1hi = (unsigned short*)(ws + 100663296);
    unsigned short* w1lo = (unsigned short*)(ws + 109051904);
    unsigned short* w2hi = (unsigned short*)(ws + 117440512);
    unsigned short* w2lo = (unsigned short*)(ws + 134217728);
    float* logits  = (float*)(ws + 150994944);
    int*   cnt     = (int*)(ws + 151060480);
    int*   ntiles  = (int*)(ws + 151060512);
    int*   tileTab = (int*)(ws + 151060544);
    float* gates   = (float*)(ws + 151061504);
    int*   list    = (int*)(ws + 151127040);
    float* outacc  = (float*)(ws);

    // zero: padded conv buffers (pad rows), and logits+cnt+ntiles in one shot
    hipMemsetAsync(ws, 0, 16908288, stream);
    hipMemsetAsync(logits, 0, 65536 + 64, stream);

    prep_all<<<16640, 256, 0, stream>>>(x, conv_w, w1, w2,
                                        xphi, xplo, wchi, wclo,
                                        w1hi, w1lo, w2hi, w2lo);

    // Router convs on MFMA (3-pass split — ~1e-7 relative, safe for discrete top-2)
    const int WL = 3 * Dd * Dd;
    conv_mfma<0><<<dim3(Bb * Ll / 64, Dd / 64), 256, 0, stream>>>(
        xphi, xplo, wchi + 0 * WL, wclo + 0 * WL, conv_b + 0 * Dd, cphi, cplo, nullptr, 1);
    conv_mfma<0><<<dim3(Bb * Ll / 64, Dd / 64), 256, 0, stream>>>(
        cphi, cplo, wchi + 1 * WL, wclo + 1 * WL, conv_b + 1 * Dd, xphi, xplo, nullptr, 2);
    conv_mfma<1><<<dim3(Bb * Ll / 64, Dd / 64), 256, 0, stream>>>(
        xphi, xplo, wchi + 2 * WL, wclo + 2 * WL, conv_b + 2 * Dd, nullptr, nullptr, hL, 4);

    logits_accum<<<dim3(Bb, 8), 256, 0, stream>>>(hL, fl_w, logits);
    gates_final<<<1, 1024, 0, stream>>>(logits, fl_b, gates, cnt, list, tileTab, ntiles);

    downsample_v3<<<dim3(64, Bb, Ee), 256, 0, stream>>>(x, xe);

    // GEMM1 sparse (gathered A from xe, K=512): h1 compact over dead conv region
    gemm_sp<0, 1><<<dim3(MAXTILES, Hh / 128), 256, 0, stream>>>(
        xe, w1hi, w1lo, b1, nullptr, cnt, list, tileTab, ntiles, h1, nullptr, NTOK, Hh, LMAXc);

    // xe dead: split w3 into its slot
    split_w4<<<8192, 256, 0, stream>>>(w3, w3hi, w3lo, Ee * Hh * Hh / 4);

    // GEMM2 sparse (compact->compact, K=1024)
    gemm_sp<0, 0><<<dim3(MAXTILES, Hh / 128), 256, 0, stream>>>(
        h1, w2hi, w2lo, b2, nullptr, cnt, list, tileTab, ntiles, h2, nullptr, NTOK, Hh, Hh);

    // h1 dead: zero outacc in its slot
    hipMemsetAsync(outacc, 0, (size_t)NTOK * Hh * sizeof(float), stream);

    // GEMM3 sparse (compact A, gated scatter-add combine)
    gemm_sp<1, 0><<<dim3(MAXTILES, Hh / 128), 256, 0, stream>>>(
        h2, w3hi, w3lo, b3, gates, cnt, list, tileTab, ntiles, nullptr, outacc, NTOK, Hh, Hh);

    transpose_out<<<dim3(Dd / 32, Hh / 32, Bb), 256, 0, stream>>>(outacc, out);
}

// Round 8
// 379.440 us; speedup vs baseline: 1.2590x; 1.0963x over previous
//
#include <hip/hip_runtime.h>
#include <math.h>

#define Bb 8
#define Ll 1024
#define Dd 256
#define Ee 8
#define Hh 1024
#define LMAXc 512
#define NTOK (Bb*Dd)   // 2048
#define LPAD 1032      // 4 + 1024 + 4 padded token rows per batch
#define MAXTILES 72    // worst-case sum_e ceil(cnt[e]/64): 4096/64 + 7

typedef short bf16x8 __attribute__((ext_vector_type(8)));
typedef float f32x4 __attribute__((ext_vector_type(4)));
typedef unsigned short u16x8 __attribute__((ext_vector_type(8)));

__device__ __forceinline__ float gelu_f(float x) {
    return 0.5f * x * (1.0f + erff(x * 0.70710678118654752440f));
}
__device__ __forceinline__ unsigned short f2b(float x) {          // RTN fp32->bf16
    unsigned int u = __float_as_uint(x);
    return (unsigned short)((u + 0x7fffu + ((u >> 16) & 1u)) >> 16);
}
__device__ __forceinline__ float b2f(unsigned short h) {
    return __uint_as_float(((unsigned int)h) << 16);
}
__device__ __forceinline__ void gl_lds16(const void* g, void* l) {
    __builtin_amdgcn_global_load_lds((const __attribute__((address_space(1))) unsigned int*)g,
                                     (__attribute__((address_space(3))) unsigned int*)l, 16, 0, 0);
}
__device__ __forceinline__ void split_one4(const float* __restrict__ src,
                                           unsigned short* __restrict__ hi,
                                           unsigned short* __restrict__ lo, int idx) {
    float4 v = ((const float4*)src)[idx];
    ushort2 h01, h23, l01, l23;
    unsigned short h;
    h = f2b(v.x); h01.x = h; l01.x = f2b(v.x - b2f(h));
    h = f2b(v.y); h01.y = h; l01.y = f2b(v.y - b2f(h));
    h = f2b(v.z); h23.x = h; l23.x = f2b(v.z - b2f(h));
    h = f2b(v.w); h23.y = h; l23.y = f2b(v.w - b2f(h));
    ((ushort2*)hi)[idx * 2] = h01; ((ushort2*)hi)[idx * 2 + 1] = h23;
    ((ushort2*)lo)[idx * 2] = l01; ((ushort2*)lo)[idx * 2 + 1] = l23;
}

// ---------------- standalone splitter (w3, launched after gemm1) ----------------
__global__ __launch_bounds__(256) void split_w4(const float* __restrict__ src,
                                                unsigned short* __restrict__ hi,
                                                unsigned short* __restrict__ lo, int n4) {
    int idx = blockIdx.x * 256 + threadIdx.x;
    if (idx >= n4) return;
    split_one4(src, hi, lo, idx);
}

// ============================================================================
// prep_all: fused prep
//   [0,2048)    : pad+split x -> [B][LPAD][D] bf16 hi/lo planes (interior)
//   [2048,4352) : conv weights [3][D][D][3] -> split planes [layer][k][o][i]
//   [4352,8448) : split w1
//   [8448,16640): split w2
// ============================================================================
__global__ __launch_bounds__(256) void prep_all(
    const float* __restrict__ x, const float* __restrict__ cw,
    const float* __restrict__ w1, const float* __restrict__ w2,
    unsigned short* __restrict__ xhi, unsigned short* __restrict__ xlo,
    unsigned short* __restrict__ wchi, unsigned short* __restrict__ wclo,
    unsigned short* __restrict__ w1hi, unsigned short* __restrict__ w1lo,
    unsigned short* __restrict__ w2hi, unsigned short* __restrict__ w2lo)
{
    int blk = blockIdx.x;
    int t = threadIdx.x;
    if (blk < 2048) {
        int idx = blk * 256 + t;                   // over B*L*D/4 = 524288
        int d4 = idx & 63;
        int l  = (idx >> 6) & 1023;
        int b  = idx >> 16;
        float4 v = ((const float4*)x)[idx];
        size_t o = ((size_t)(b * LPAD + 4 + l) * Dd + d4 * 4) >> 1;
        ushort2 h01, h23, l01, l23;
        unsigned short h;
        h = f2b(v.x); h01.x = h; l01.x = f2b(v.x - b2f(h));
        h = f2b(v.y); h01.y = h; l01.y = f2b(v.y - b2f(h));
        h = f2b(v.z); h23.x = h; l23.x = f2b(v.z - b2f(h));
        h = f2b(v.w); h23.y = h; l23.y = f2b(v.w - b2f(h));
        ((ushort2*)xhi)[o] = h01; ((ushort2*)xhi)[o + 1] = h23;
        ((ushort2*)xlo)[o] = l01; ((ushort2*)xlo)[o + 1] = l23;
    } else if (blk < 4352) {
        int idx = (blk - 2048) * 256 + t;          // 589824 exact
        int i = idx & (Dd - 1);
        int o = (idx >> 8) & (Dd - 1);
        int lk = idx >> 16;
        int layer = lk / 3;
        int k = lk % 3;
        float v = cw[(((size_t)layer * Dd + o) * Dd + i) * 3 + k];
        unsigned short h = f2b(v);
        wchi[idx] = h;
        wclo[idx] = f2b(v - b2f(h));
    } else if (blk < 8448) {
        split_one4(w1, w1hi, w1lo, (blk - 4352) * 256 + t);
    } else {
        split_one4(w2, w2hi, w2lo, (blk - 8448) * 256 + t);
    }
}

// ============================================================================
// conv_mfma: dilated causal-'same' conv as MFMA NT-GEMM over 3 shifted taps.
// 3-pass split-bf16 (router precision). 64x64 tile, 4 waves (2x2 of 32x32).
// ============================================================================
template<int MODE>
__global__ __launch_bounds__(256, 2) void conv_mfma(
    const unsigned short* __restrict__ inhi, const unsigned short* __restrict__ inlo,
    const unsigned short* __restrict__ whiL, const unsigned short* __restrict__ wloL,
    const float* __restrict__ bias,
    unsigned short* __restrict__ outhi, unsigned short* __restrict__ outlo,
    float* __restrict__ outf, int dil)
{
    __shared__ char smem[16384];
    char* sAhi = smem;
    char* sAlo = smem + 4096;
    char* sBhi = smem + 8192;
    char* sBlo = smem + 12288;

    const int t = threadIdx.x;
    const int lane = t & 63, w = t >> 6;
    const int r16 = lane & 15, quad = lane >> 4;
    const int wr = w >> 1, wc = w & 1;
    const int row0 = blockIdx.x * 64;
    const int col0 = blockIdx.y * 64;
    const int b = row0 >> 10, l0 = row0 & 1023;

    int aoff[2], boff[2];
    #pragma unroll
    for (int i = 0; i < 2; ++i) {
        int ra = wr * 32 + i * 16 + r16;
        aoff[i] = ra * 64 + ((quad ^ ((ra >> 1) & 3)) << 4);
        int rb = wc * 32 + i * 16 + r16;
        boff[i] = rb * 64 + ((quad ^ ((rb >> 1) & 3)) << 4);
    }
    const int rs = t >> 2, ce = ((t & 3) ^ ((rs >> 1) & 3)) << 3;
    const unsigned short* gAhi = inhi + (size_t)(b * LPAD + 4 + l0 + rs) * Dd + ce;
    const unsigned short* gAlo = inlo + (size_t)(b * LPAD + 4 + l0 + rs) * Dd + ce;

    f32x4 acc[2][2];
    const f32x4 zero4 = {0.f, 0.f, 0.f, 0.f};
    #pragma unroll
    for (int i = 0; i < 2; ++i)
        #pragma unroll
        for (int j = 0; j < 2; ++j) acc[i][j] = zero4;

    for (int tap = 0; tap < 3; ++tap) {
        const int sh = (tap - 1) * dil;
        const unsigned short* pAhi = gAhi + sh * Dd;
        const unsigned short* pAlo = gAlo + sh * Dd;
        const unsigned short* gBhi = whiL + ((size_t)tap * Dd + col0 + rs) * Dd + ce;
        const unsigned short* gBlo = wloL + ((size_t)tap * Dd + col0 + rs) * Dd + ce;
        for (int kb = 0; kb < Dd; kb += 32) {
            gl_lds16(pAhi + kb, sAhi + (w << 10));
            gl_lds16(pAlo + kb, sAlo + (w << 10));
            gl_lds16(gBhi + kb, sBhi + (w << 10));
            gl_lds16(gBlo + kb, sBlo + (w << 10));
            __syncthreads();
            bf16x8 ah[2], al[2], bh[2], bl[2];
            #pragma unroll
            for (int i = 0; i < 2; ++i) {
                ah[i] = *(const bf16x8*)(sAhi + aoff[i]);
                al[i] = *(const bf16x8*)(sAlo + aoff[i]);
                bh[i] = *(const bf16x8*)(sBhi + boff[i]);
                bl[i] = *(const bf16x8*)(sBlo + boff[i]);
            }
            #pragma unroll
            for (int mi = 0; mi < 2; ++mi)
                #pragma unroll
                for (int ni = 0; ni < 2; ++ni) {
                    acc[mi][ni] = __builtin_amdgcn_mfma_f32_16x16x32_bf16(ah[mi], bh[ni], acc[mi][ni], 0, 0, 0);
                    acc[mi][ni] = __builtin_amdgcn_mfma_f32_16x16x32_bf16(ah[mi], bl[ni], acc[mi][ni], 0, 0, 0);
                    acc[mi][ni] = __builtin_amdgcn_mfma_f32_16x16x32_bf16(al[mi], bh[ni], acc[mi][ni], 0, 0, 0);
                }
            __syncthreads();
        }
    }

    int cc[2]; float bv[2];
    #pragma unroll
    for (int ni = 0; ni < 2; ++ni) {
        cc[ni] = col0 + wc * 32 + ni * 16 + r16;
        bv[ni] = bias[cc[ni]];
    }
    #pragma unroll
    for (int mi = 0; mi < 2; ++mi) {
        int lb = l0 + wr * 32 + mi * 16 + quad * 4;
        #pragma unroll
        for (int reg = 0; reg < 4; ++reg) {
            int l = lb + reg;
            #pragma unroll
            for (int ni = 0; ni < 2; ++ni) {
                float v = gelu_f(acc[mi][ni][reg] + bv[ni]);
                if (MODE == 0) {
                    size_t o = (size_t)(b * LPAD + 4 + l) * Dd + cc[ni];
                    unsigned short h = f2b(v);
                    outhi[o] = h;
                    outlo[o] = f2b(v - b2f(h));
                } else {
                    outf[(size_t)(b * Ll + l) * Dd + cc[ni]] = v;
                }
            }
        }
    }
}

// ============================================================================
// Sparse expert GEMM v3: balanced flat tile dispatch, XCD-aligned N-strips.
// Grid (Hh/128 = 8, MAXTILES): blockIdx.x = N-strip. With x-fastest linear
// block ids and round-robin block->XCD, XCD == N-strip: each XCD's L2 holds
// only strip n of each expert's B (4 MB total) -> B fetched ~once from HBM.
// Tile M=64 x N=128, 4 waves (2x2, wave-tile 32x64), BK=32, 2-pass split-bf16.
// tileTab[i] = (e<<16)|mtile (e-major => same-XCD blocks reuse the hot strip).
// ============================================================================
template<int MODE, int GATHER>
__global__ __launch_bounds__(256, 4) void gemm_sp(
    const unsigned short* __restrict__ AG,
    const unsigned short* __restrict__ BhiG, const unsigned short* __restrict__ BloG,
    const float* __restrict__ biasG, const float* __restrict__ gates,
    const int* __restrict__ cntG, const int* __restrict__ listG,
    const int* __restrict__ tileTab, const int* __restrict__ ntiles,
    unsigned short* __restrict__ Cout, float* __restrict__ outf,
    int M, int N, int K)
{
    if (blockIdx.y >= ntiles[0]) return;          // uniform early-exit
    const int desc = tileTab[blockIdx.y];
    const int e = desc >> 16;
    const int row0 = (desc & 0xffff) * 64;
    const int cn = cntG[e];

    __shared__ char smem[20480];                  // A 4K | Bhi 8K | Blo 8K
    char* sA   = smem;
    char* sBhi = smem + 4096;
    char* sBlo = smem + 12288;

    const unsigned short* Bhi = BhiG + (size_t)e * N * K;
    const unsigned short* Blo = BloG + (size_t)e * N * K;
    const float* bias = biasG + (size_t)e * N;

    const int t = threadIdx.x;
    const int lane = t & 63, w = t >> 6;
    const int r16 = lane & 15, quad = lane >> 4;
    const int wr = w >> 1, wc = w & 1;
    const int col0 = blockIdx.x * 128;

    int aoff[2], boff[4];
    #pragma unroll
    for (int i = 0; i < 2; ++i) {
        int ra = wr * 32 + i * 16 + r16;
        aoff[i] = ra * 64 + ((quad ^ ((ra >> 1) & 3)) << 4);
    }
    #pragma unroll
    for (int j = 0; j < 4; ++j) {
        int rb = wc * 64 + j * 16 + r16;
        boff[j] = rb * 64 + ((quad ^ ((rb >> 1) & 3)) << 4);
    }
    // staging: A 256 slots (slot t); B 512 slots/plane (slots t, t+256)
    const int r0s = t >> 2, c0s = ((t & 3) ^ ((r0s >> 1) & 3)) << 3;
    const int r1s = r0s + 64, c1s = ((t & 3) ^ ((r1s >> 1) & 3)) << 3;
    int ri = row0 + r0s; if (ri > cn - 1) ri = cn - 1;
    const int ar = GATHER ? listG[e * NTOK + ri] : ri;
    const unsigned short* gA  = AG + ((size_t)e * M + ar) * K + c0s;
    const unsigned short* gBhi0 = Bhi + (size_t)(col0 + r0s) * K + c0s;
    const unsigned short* gBhi1 = Bhi + (size_t)(col0 + r1s) * K + c1s;
    const unsigned short* gBlo0 = Blo + (size_t)(col0 + r0s) * K + c0s;
    const unsigned short* gBlo1 = Blo + (size_t)(col0 + r1s) * K + c1s;

    f32x4 acc[2][4];
    const f32x4 zero4 = {0.f, 0.f, 0.f, 0.f};
    #pragma unroll
    for (int i = 0; i < 2; ++i)
        #pragma unroll
        for (int j = 0; j < 4; ++j) acc[i][j] = zero4;

    for (int k0 = 0; k0 < K; k0 += 32) {
        gl_lds16(gA + k0, sA + (w << 10));
        gl_lds16(gBhi0 + k0, sBhi + (w << 10));
        gl_lds16(gBhi1 + k0, sBhi + 4096 + (w << 10));
        gl_lds16(gBlo0 + k0, sBlo + (w << 10));
        gl_lds16(gBlo1 + k0, sBlo + 4096 + (w << 10));
        __syncthreads();
        bf16x8 ah[2], bh[4], bl[4];
        #pragma unroll
        for (int i = 0; i < 2; ++i) ah[i] = *(const bf16x8*)(sA + aoff[i]);
        #pragma unroll
        for (int j = 0; j < 4; ++j) {
            bh[j] = *(const bf16x8*)(sBhi + boff[j]);
            bl[j] = *(const bf16x8*)(sBlo + boff[j]);
        }
        #pragma unroll
        for (int mi = 0; mi < 2; ++mi)
            #pragma unroll
            for (int ni = 0; ni < 4; ++ni) {
                acc[mi][ni] = __builtin_amdgcn_mfma_f32_16x16x32_bf16(ah[mi], bh[ni], acc[mi][ni], 0, 0, 0);
                acc[mi][ni] = __builtin_amdgcn_mfma_f32_16x16x32_bf16(ah[mi], bl[ni], acc[mi][ni], 0, 0, 0);
            }
        __syncthreads();
    }

    int cc[4]; float bv[4];
    #pragma unroll
    for (int ni = 0; ni < 4; ++ni) {
        cc[ni] = col0 + wc * 64 + ni * 16 + r16;
        bv[ni] = bias[cc[ni]];
    }
    if (MODE == 0) {
        unsigned short* CE = Cout + (size_t)e * M * N;
        #pragma unroll
        for (int mi = 0; mi < 2; ++mi) {
            int rb = row0 + wr * 32 + mi * 16 + quad * 4;
            #pragma unroll
            for (int reg = 0; reg < 4; ++reg) {
                size_t roff = (size_t)(rb + reg) * N;
                #pragma unroll
                for (int ni = 0; ni < 4; ++ni)
                    CE[roff + cc[ni]] = f2b(gelu_f(acc[mi][ni][reg] + bv[ni]));
            }
        }
    } else {
        #pragma unroll
        for (int mi = 0; mi < 2; ++mi) {
            int rb = row0 + wr * 32 + mi * 16 + quad * 4;
            #pragma unroll
            for (int reg = 0; reg < 4; ++reg) {
                int i = rb + reg;
                if (i < cn) {
                    int tok = listG[e * NTOK + i];
                    float g = gates[(size_t)tok * Ee + e];
                    size_t roff = (size_t)tok * N;
                    #pragma unroll
                    for (int ni = 0; ni < 4; ++ni)
                        atomicAdd(&outf[roff + cc[ni]], g * (acc[mi][ni][reg] + bv[ni]));
                }
            }
        }
    }
}

// ============================ router tail + downsample ==============================

__global__ __launch_bounds__(256) void logits_accum(const float* __restrict__ h,
                                                    const float* __restrict__ fl_w,
                                                    float* __restrict__ logits) {
    int b = blockIdx.x;
    int chunk = blockIdx.y;
    __shared__ float wsm[Ee][128];
    for (int i = threadIdx.x; i < Ee * 128; i += 256) {
        int e = i >> 7, l = i & 127;
        wsm[e][l] = fl_w[e * Ll + chunk * 128 + l];
    }
    __syncthreads();
    int d = threadIdx.x;
    float acc[Ee] = {};
    for (int l = 0; l < 128; ++l) {
        float v = h[((size_t)b * Ll + chunk * 128 + l) * Dd + d];
        #pragma unroll
        for (int e = 0; e < Ee; ++e) acc[e] += v * wsm[e][l];
    }
    int tok = b * Dd + d;
    #pragma unroll
    for (int e = 0; e < Ee; ++e) atomicAdd(&logits[tok * Ee + e], acc[e]);
}

// sigmoid -> softmax -> top2 -> gates + per-expert lists + balanced tile table.
// ONE block of 1024 threads (2 toks each) so cnt is final before table build.
__global__ __launch_bounds__(1024) void gates_final(const float* __restrict__ logits,
                                                    const float* __restrict__ fl_b,
                                                    float* __restrict__ gates,
                                                    int* __restrict__ cnt,
                                                    int* __restrict__ list,
                                                    int* __restrict__ tileTab,
                                                    int* __restrict__ ntiles) {
    for (int tok = threadIdx.x; tok < NTOK; tok += 1024) {
        float s[Ee];
        #pragma unroll
        for (int e = 0; e < Ee; ++e) {
            float z = logits[tok * Ee + e] + fl_b[e];
            s[e] = 1.0f / (1.0f + expf(-z));
        }
        float mx = s[0];
        #pragma unroll
        for (int e = 1; e < Ee; ++e) mx = fmaxf(mx, s[e]);
        float p[Ee];
        #pragma unroll
        for (int e = 0; e < Ee; ++e) p[e] = expf(s[e] - mx);
        int i1 = 0;
        #pragma unroll
        for (int e = 1; e < Ee; ++e) if (p[e] > p[i1]) i1 = e;
        int i2 = (i1 == 0) ? 1 : 0;
        #pragma unroll
        for (int e = 0; e < Ee; ++e) {
            if (e == i1 || e == i2) continue;
            if (p[e] > p[i2]) i2 = e;
        }
        float inv = 1.0f / (p[i1] + p[i2]);
        #pragma unroll
        for (int e = 0; e < Ee; ++e) gates[tok * Ee + e] = 0.0f;
        gates[tok * Ee + i1] = p[i1] * inv;
        gates[tok * Ee + i2] = p[i2] * inv;
        int p1 = atomicAdd(&cnt[i1], 1);
        list[i1 * NTOK + p1] = tok;
        int p2 = atomicAdd(&cnt[i2], 1);
        list[i2 * NTOK + p2] = tok;
    }
    __syncthreads();
    if (threadIdx.x == 0) {
        int nt = 0;
        for (int e = 0; e < Ee; ++e) {
            int c = atomicAdd(&cnt[e], 0);        // coherent read (atomics bypass L1)
            for (int m = 0; m * 64 < c; ++m) tileTab[nt++] = (e << 16) | m;
        }
        ntiles[0] = nt;
    }
}

// downsample v3: single bf16 plane, valid region only (xe pad cols hit zero
// w1 cols). 8 j/thread, r-outer for load ILP; early-exit past Li.
__global__ __launch_bounds__(256) void downsample_v3(const float* __restrict__ x,
                                                     unsigned short* __restrict__ xe) {
    int e = blockIdx.z;
    int f = e + 2;
    int Li = Ll / f;
    int j0 = blockIdx.x * 8;
    if (j0 >= Li) return;
    int b = blockIdx.y;
    int d = threadIdx.x;
    float invf = 1.0f / (float)f;
    int lim = Li - 1;
    float v[8] = {};
    for (int r = 0; r < f; ++r) {
        #pragma unroll
        for (int jj = 0; jj < 8; ++jj) {
            int j = j0 + jj; if (j > lim) j = lim;
            v[jj] += x[((size_t)(b * Ll + j * f + r)) * Dd + d];
        }
    }
    size_t obase = ((size_t)(e * NTOK + b * 256 + d)) * LMAXc + j0;
    if (j0 + 8 <= Li) {
        u16x8 hv;
        #pragma unroll
        for (int q = 0; q < 8; ++q) hv[q] = (short)f2b(v[q] * invf);
        *(u16x8*)(xe + obase) = hv;
    } else {
        for (int jj = 0; jj < Li - j0; ++jj)
            xe[obase + jj] = f2b(v[jj] * invf);
    }
}

__global__ __launch_bounds__(256) void transpose_out(const float* __restrict__ outacc,
                                                     float* __restrict__ out) {
    __shared__ float tile[32][33];
    int b = blockIdx.z;
    int d0 = blockIdx.x * 32;
    int o0 = blockIdx.y * 32;
    int tx = threadIdx.x & 31, ty = threadIdx.x >> 5;
    for (int i = 0; i < 32; i += 8)
        tile[ty + i][tx] = outacc[((size_t)b * Dd + d0 + ty + i) * Hh + o0 + tx];
    __syncthreads();
    for (int i = 0; i < 32; i += 8)
        out[((size_t)b * Hh + o0 + ty + i) * Dd + d0 + tx] = tile[tx][ty + i];
}

extern "C" void kernel_launch(void* const* d_in, const int* in_sizes, int n_in,
                              void* d_out, int out_size, void* d_ws, size_t ws_size,
                              hipStream_t stream) {
    const float* x       = (const float*)d_in[0];
    const float* conv_w  = (const float*)d_in[1];
    const float* conv_b  = (const float*)d_in[2];
    const float* fl_w    = (const float*)d_in[3];
    const float* fl_b    = (const float*)d_in[4];
    const float* w1      = (const float*)d_in[5];
    const float* b1      = (const float*)d_in[6];
    const float* w2      = (const float*)d_in[7];
    const float* b2      = (const float*)d_in[8];
    const float* w3      = (const float*)d_in[9];
    const float* b3      = (const float*)d_in[10];
    float* out = (float*)d_out;

    char* ws = (char*)d_ws;
    // Workspace (peak ~151.2 MB, proven). h1 region overlaid by conv buffers
    // until gemm1, then by outacc after gemm2 (layout identical to R7).
    unsigned short* xphi = (unsigned short*)(ws);
    unsigned short* xplo = (unsigned short*)(ws + 4227072);
    unsigned short* cphi = (unsigned short*)(ws + 8454144);
    unsigned short* cplo = (unsigned short*)(ws + 12681216);
    unsigned short* wchi = (unsigned short*)(ws + 16908288);
    unsigned short* wclo = (unsigned short*)(ws + 18087936);
    float* hL            = (float*)(ws + 19267584);
    unsigned short* h1   = (unsigned short*)(ws);
    unsigned short* h2   = (unsigned short*)(ws + 33554432);
    unsigned short* xe   = (unsigned short*)(ws + 67108864);
    unsigned short* w3hi = (unsigned short*)(ws + 67108864);
    unsigned short* w3lo = (unsigned short*)(ws + 83886080);
    unsigned short* w1hi = (unsigned short*)(ws + 100663296);
    unsigned short* w1lo = (unsigned short*)(ws + 109051904);
    unsigned short* w2hi = (unsigned short*)(ws + 117440512);
    unsigned short* w2lo = (unsigned short*)(ws + 134217728);
    float* logits  = (float*)(ws + 150994944);
    int*   cnt     = (int*)(ws + 151060480);
    int*   ntiles  = (int*)(ws + 151060512);
    int*   tileTab = (int*)(ws + 151060544);
    float* gates   = (float*)(ws + 151061504);
    int*   list    = (int*)(ws + 151127040);
    float* outacc  = (float*)(ws);

    // zero: padded conv buffers (pad rows), and logits+cnt+ntiles in one shot
    hipMemsetAsync(ws, 0, 16908288, stream);
    hipMemsetAsync(logits, 0, 65536 + 64, stream);

    prep_all<<<16640, 256, 0, stream>>>(x, conv_w, w1, w2,
                                        xphi, xplo, wchi, wclo,
                                        w1hi, w1lo, w2hi, w2lo);

    // Router convs on MFMA (3-pass split — ~1e-7 relative, safe for discrete top-2)
    const int WL = 3 * Dd * Dd;
    conv_mfma<0><<<dim3(Bb * Ll / 64, Dd / 64), 256, 0, stream>>>(
        xphi, xplo, wchi + 0 * WL, wclo + 0 * WL, conv_b + 0 * Dd, cphi, cplo, nullptr, 1);
    conv_mfma<0><<<dim3(Bb * Ll / 64, Dd / 64), 256, 0, stream>>>(
        cphi, cplo, wchi + 1 * WL, wclo + 1 * WL, conv_b + 1 * Dd, xphi, xplo, nullptr, 2);
    conv_mfma<1><<<dim3(Bb * Ll / 64, Dd / 64), 256, 0, stream>>>(
        xphi, xplo, wchi + 2 * WL, wclo + 2 * WL, conv_b + 2 * Dd, nullptr, nullptr, hL, 4);

    logits_accum<<<dim3(Bb, 8), 256, 0, stream>>>(hL, fl_w, logits);
    gates_final<<<1, 1024, 0, stream>>>(logits, fl_b, gates, cnt, list, tileTab, ntiles);

    downsample_v3<<<dim3(64, Bb, Ee), 256, 0, stream>>>(x, xe);

    // GEMM1 sparse (gathered A from xe, K=512): h1 compact over dead conv region
    gemm_sp<0, 1><<<dim3(Hh / 128, MAXTILES), 256, 0, stream>>>(
        xe, w1hi, w1lo, b1, nullptr, cnt, list, tileTab, ntiles, h1, nullptr, NTOK, Hh, LMAXc);

    // xe dead: split w3 into its slot
    split_w4<<<8192, 256, 0, stream>>>(w3, w3hi, w3lo, Ee * Hh * Hh / 4);

    // GEMM2 sparse (compact->compact, K=1024)
    gemm_sp<0, 0><<<dim3(Hh / 128, MAXTILES), 256, 0, stream>>>(
        h1, w2hi, w2lo, b2, nullptr, cnt, list, tileTab, ntiles, h2, nullptr, NTOK, Hh, Hh);

    // h1 dead: zero outacc in its slot
    hipMemsetAsync(outacc, 0, (size_t)NTOK * Hh * sizeof(float), stream);

    // GEMM3 sparse (compact A, gated scatter-add combine)
    gemm_sp<1, 0><<<dim3(Hh / 128, MAXTILES), 256, 0, stream>>>(
        h2, w3hi, w3lo, b3, gates, cnt, list, tileTab, ntiles, nullptr, outacc, NTOK, Hh, Hh);

    transpose_out<<<dim3(Dd / 32, Hh / 32, Bb), 256, 0, stream>>>(outacc, out);
}

// Round 9
// 359.776 us; speedup vs baseline: 1.3278x; 1.0547x over previous
//
#include <hip/hip_runtime.h>
#include <math.h>

#define Bb 8
#define Ll 1024
#define Dd 256
#define Ee 8
#define Hh 1024
#define LMAXc 512
#define NTOK (Bb*Dd)   // 2048
#define LPAD 1032      // 4 + 1024 + 4 padded token rows per batch
#define MAXTILES 72    // worst-case sum_e ceil(cnt[e]/64): 4096/64 + 7

typedef short bf16x8 __attribute__((ext_vector_type(8)));
typedef float f32x4 __attribute__((ext_vector_type(4)));
typedef unsigned short u16x8 __attribute__((ext_vector_type(8)));

__device__ __forceinline__ float gelu_f(float x) {
    return 0.5f * x * (1.0f + erff(x * 0.70710678118654752440f));
}
__device__ __forceinline__ unsigned short f2b(float x) {          // RTN fp32->bf16
    unsigned int u = __float_as_uint(x);
    return (unsigned short)((u + 0x7fffu + ((u >> 16) & 1u)) >> 16);
}
__device__ __forceinline__ float b2f(unsigned short h) {
    return __uint_as_float(((unsigned int)h) << 16);
}
__device__ __forceinline__ void gl_lds16(const void* g, void* l) {
    __builtin_amdgcn_global_load_lds((const __attribute__((address_space(1))) unsigned int*)g,
                                     (__attribute__((address_space(3))) unsigned int*)l, 16, 0, 0);
}
__device__ __forceinline__ void split_one4(const float* __restrict__ src,
                                           unsigned short* __restrict__ hi,
                                           unsigned short* __restrict__ lo, int idx) {
    float4 v = ((const float4*)src)[idx];
    ushort2 h01, h23, l01, l23;
    unsigned short h;
    h = f2b(v.x); h01.x = h; l01.x = f2b(v.x - b2f(h));
    h = f2b(v.y); h01.y = h; l01.y = f2b(v.y - b2f(h));
    h = f2b(v.z); h23.x = h; l23.x = f2b(v.z - b2f(h));
    h = f2b(v.w); h23.y = h; l23.y = f2b(v.w - b2f(h));
    ((ushort2*)hi)[idx * 2] = h01; ((ushort2*)hi)[idx * 2 + 1] = h23;
    ((ushort2*)lo)[idx * 2] = l01; ((ushort2*)lo)[idx * 2 + 1] = l23;
}

// ---------------- standalone splitter (w3, launched after gemm1) ----------------
__global__ __launch_bounds__(256) void split_w4(const float* __restrict__ src,
                                                unsigned short* __restrict__ hi,
                                                unsigned short* __restrict__ lo, int n4) {
    int idx = blockIdx.x * 256 + threadIdx.x;
    if (idx >= n4) return;
    split_one4(src, hi, lo, idx);
}

// ============================================================================
// prep_all: fused prep
//   [0,2048)    : pad+split x -> [B][LPAD][D] bf16 hi/lo planes (interior)
//   [2048,4352) : conv weights [3][D][D][3] -> split planes [layer][k][o][i]
//   [4352,8448) : split w1
//   [8448,16640): split w2
// ============================================================================
__global__ __launch_bounds__(256) void prep_all(
    const float* __restrict__ x, const float* __restrict__ cw,
    const float* __restrict__ w1, const float* __restrict__ w2,
    unsigned short* __restrict__ xhi, unsigned short* __restrict__ xlo,
    unsigned short* __restrict__ wchi, unsigned short* __restrict__ wclo,
    unsigned short* __restrict__ w1hi, unsigned short* __restrict__ w1lo,
    unsigned short* __restrict__ w2hi, unsigned short* __restrict__ w2lo)
{
    int blk = blockIdx.x;
    int t = threadIdx.x;
    if (blk < 2048) {
        int idx = blk * 256 + t;                   // over B*L*D/4 = 524288
        int d4 = idx & 63;
        int l  = (idx >> 6) & 1023;
        int b  = idx >> 16;
        float4 v = ((const float4*)x)[idx];
        size_t o = ((size_t)(b * LPAD + 4 + l) * Dd + d4 * 4) >> 1;
        ushort2 h01, h23, l01, l23;
        unsigned short h;
        h = f2b(v.x); h01.x = h; l01.x = f2b(v.x - b2f(h));
        h = f2b(v.y); h01.y = h; l01.y = f2b(v.y - b2f(h));
        h = f2b(v.z); h23.x = h; l23.x = f2b(v.z - b2f(h));
        h = f2b(v.w); h23.y = h; l23.y = f2b(v.w - b2f(h));
        ((ushort2*)xhi)[o] = h01; ((ushort2*)xhi)[o + 1] = h23;
        ((ushort2*)xlo)[o] = l01; ((ushort2*)xlo)[o + 1] = l23;
    } else if (blk < 4352) {
        int idx = (blk - 2048) * 256 + t;          // 589824 exact
        int i = idx & (Dd - 1);
        int o = (idx >> 8) & (Dd - 1);
        int lk = idx >> 16;
        int layer = lk / 3;
        int k = lk % 3;
        float v = cw[(((size_t)layer * Dd + o) * Dd + i) * 3 + k];
        unsigned short h = f2b(v);
        wchi[idx] = h;
        wclo[idx] = f2b(v - b2f(h));
    } else if (blk < 8448) {
        split_one4(w1, w1hi, w1lo, (blk - 4352) * 256 + t);
    } else {
        split_one4(w2, w2hi, w2lo, (blk - 8448) * 256 + t);
    }
}

// ============================================================================
// conv_mfma: dilated causal-'same' conv as MFMA NT-GEMM over 3 shifted taps.
// 3-pass split-bf16 (router precision). 64x64 tile, 4 waves (2x2 of 32x32).
// BK=64 (two 32-chunks per barrier pair) -> 12 k-iters instead of 24.
// ============================================================================
template<int MODE>
__global__ __launch_bounds__(256, 2) void conv_mfma(
    const unsigned short* __restrict__ inhi, const unsigned short* __restrict__ inlo,
    const unsigned short* __restrict__ whiL, const unsigned short* __restrict__ wloL,
    const float* __restrict__ bias,
    unsigned short* __restrict__ outhi, unsigned short* __restrict__ outlo,
    float* __restrict__ outf, int dil)
{
    __shared__ char smem[32768];   // Ahi 8K | Alo 8K | Bhi 8K | Blo 8K (each 2 halves of 4K)
    char* sAhi = smem;
    char* sAlo = smem + 8192;
    char* sBhi = smem + 16384;
    char* sBlo = smem + 24576;

    const int t = threadIdx.x;
    const int lane = t & 63, w = t >> 6;
    const int r16 = lane & 15, quad = lane >> 4;
    const int wr = w >> 1, wc = w & 1;
    const int row0 = blockIdx.x * 64;
    const int col0 = blockIdx.y * 64;
    const int b = row0 >> 10, l0 = row0 & 1023;

    int aoff[2], boff[2];
    #pragma unroll
    for (int i = 0; i < 2; ++i) {
        int ra = wr * 32 + i * 16 + r16;
        aoff[i] = ra * 64 + ((quad ^ ((ra >> 1) & 3)) << 4);
        int rb = wc * 32 + i * 16 + r16;
        boff[i] = rb * 64 + ((quad ^ ((rb >> 1) & 3)) << 4);
    }
    const int rs = t >> 2, ce = ((t & 3) ^ ((rs >> 1) & 3)) << 3;
    const unsigned short* gAhi = inhi + (size_t)(b * LPAD + 4 + l0 + rs) * Dd + ce;
    const unsigned short* gAlo = inlo + (size_t)(b * LPAD + 4 + l0 + rs) * Dd + ce;

    f32x4 acc[2][2];
    const f32x4 zero4 = {0.f, 0.f, 0.f, 0.f};
    #pragma unroll
    for (int i = 0; i < 2; ++i)
        #pragma unroll
        for (int j = 0; j < 2; ++j) acc[i][j] = zero4;

    for (int tap = 0; tap < 3; ++tap) {
        const int sh = (tap - 1) * dil;
        const unsigned short* pAhi = gAhi + sh * Dd;
        const unsigned short* pAlo = gAlo + sh * Dd;
        const unsigned short* gBhi = whiL + ((size_t)tap * Dd + col0 + rs) * Dd + ce;
        const unsigned short* gBlo = wloL + ((size_t)tap * Dd + col0 + rs) * Dd + ce;
        for (int kb = 0; kb < Dd; kb += 64) {
            gl_lds16(pAhi + kb,      sAhi + (w << 10));
            gl_lds16(pAhi + kb + 32, sAhi + 4096 + (w << 10));
            gl_lds16(pAlo + kb,      sAlo + (w << 10));
            gl_lds16(pAlo + kb + 32, sAlo + 4096 + (w << 10));
            gl_lds16(gBhi + kb,      sBhi + (w << 10));
            gl_lds16(gBhi + kb + 32, sBhi + 4096 + (w << 10));
            gl_lds16(gBlo + kb,      sBlo + (w << 10));
            gl_lds16(gBlo + kb + 32, sBlo + 4096 + (w << 10));
            __syncthreads();
            #pragma unroll
            for (int h = 0; h < 2; ++h) {
                const int ho = h * 4096;
                bf16x8 ah[2], al[2], bh[2], bl[2];
                #pragma unroll
                for (int i = 0; i < 2; ++i) {
                    ah[i] = *(const bf16x8*)(sAhi + ho + aoff[i]);
                    al[i] = *(const bf16x8*)(sAlo + ho + aoff[i]);
                    bh[i] = *(const bf16x8*)(sBhi + ho + boff[i]);
                    bl[i] = *(const bf16x8*)(sBlo + ho + boff[i]);
                }
                #pragma unroll
                for (int mi = 0; mi < 2; ++mi)
                    #pragma unroll
                    for (int ni = 0; ni < 2; ++ni) {
                        acc[mi][ni] = __builtin_amdgcn_mfma_f32_16x16x32_bf16(ah[mi], bh[ni], acc[mi][ni], 0, 0, 0);
                        acc[mi][ni] = __builtin_amdgcn_mfma_f32_16x16x32_bf16(ah[mi], bl[ni], acc[mi][ni], 0, 0, 0);
                        acc[mi][ni] = __builtin_amdgcn_mfma_f32_16x16x32_bf16(al[mi], bh[ni], acc[mi][ni], 0, 0, 0);
                    }
            }
            __syncthreads();
        }
    }

    int cc[2]; float bv[2];
    #pragma unroll
    for (int ni = 0; ni < 2; ++ni) {
        cc[ni] = col0 + wc * 32 + ni * 16 + r16;
        bv[ni] = bias[cc[ni]];
    }
    #pragma unroll
    for (int mi = 0; mi < 2; ++mi) {
        int lb = l0 + wr * 32 + mi * 16 + quad * 4;
        #pragma unroll
        for (int reg = 0; reg < 4; ++reg) {
            int l = lb + reg;
            #pragma unroll
            for (int ni = 0; ni < 2; ++ni) {
                float v = gelu_f(acc[mi][ni][reg] + bv[ni]);
                if (MODE == 0) {
                    size_t o = (size_t)(b * LPAD + 4 + l) * Dd + cc[ni];
                    unsigned short h = f2b(v);
                    outhi[o] = h;
                    outlo[o] = f2b(v - b2f(h));
                } else {
                    outf[(size_t)(b * Ll + l) * Dd + cc[ni]] = v;
                }
            }
        }
    }
}

// ============================================================================
// Sparse expert GEMM v4: balanced flat tile dispatch, XCD-aligned N-strips,
// BK=64 (two 32-chunks per barrier pair -> half the vmcnt/barrier drains).
// Grid (Hh/128 = 8, MAXTILES): blockIdx.x = N-strip == XCD (L2 locality).
// Tile M=64 x N=128, 4 waves (2x2, wave-tile 32x64), 2-pass split-bf16.
// LDS 40KB; __launch_bounds__(256,4): 4 blocks/CU x 40KB = 160KB = LDS cap.
// ============================================================================
template<int MODE, int GATHER>
__global__ __launch_bounds__(256, 4) void gemm_sp(
    const unsigned short* __restrict__ AG,
    const unsigned short* __restrict__ BhiG, const unsigned short* __restrict__ BloG,
    const float* __restrict__ biasG, const float* __restrict__ gates,
    const int* __restrict__ cntG, const int* __restrict__ listG,
    const int* __restrict__ tileTab, const int* __restrict__ ntiles,
    unsigned short* __restrict__ Cout, float* __restrict__ outf,
    int M, int N, int K)
{
    if (blockIdx.y >= ntiles[0]) return;          // uniform early-exit
    const int desc = tileTab[blockIdx.y];
    const int e = desc >> 16;
    const int row0 = (desc & 0xffff) * 64;
    const int cn = cntG[e];

    __shared__ char smem[40960];                  // A 8K (2x4K) | Bhi 16K (2x8K) | Blo 16K
    char* sA   = smem;
    char* sBhi = smem + 8192;
    char* sBlo = smem + 24576;

    const unsigned short* Bhi = BhiG + (size_t)e * N * K;
    const unsigned short* Blo = BloG + (size_t)e * N * K;
    const float* bias = biasG + (size_t)e * N;

    const int t = threadIdx.x;
    const int lane = t & 63, w = t >> 6;
    const int r16 = lane & 15, quad = lane >> 4;
    const int wr = w >> 1, wc = w & 1;
    const int col0 = blockIdx.x * 128;

    int aoff[2], boff[4];
    #pragma unroll
    for (int i = 0; i < 2; ++i) {
        int ra = wr * 32 + i * 16 + r16;
        aoff[i] = ra * 64 + ((quad ^ ((ra >> 1) & 3)) << 4);
    }
    #pragma unroll
    for (int j = 0; j < 4; ++j) {
        int rb = wc * 64 + j * 16 + r16;
        boff[j] = rb * 64 + ((quad ^ ((rb >> 1) & 3)) << 4);
    }
    // staging: A 256 slots (slot t); B 512 slots/plane-half (slots t, t+256)
    const int r0s = t >> 2, c0s = ((t & 3) ^ ((r0s >> 1) & 3)) << 3;
    const int r1s = r0s + 64, c1s = ((t & 3) ^ ((r1s >> 1) & 3)) << 3;
    int ri = row0 + r0s; if (ri > cn - 1) ri = cn - 1;
    const int ar = GATHER ? listG[e * NTOK + ri] : ri;
    const unsigned short* gA  = AG + ((size_t)e * M + ar) * K + c0s;
    const unsigned short* gBhi0 = Bhi + (size_t)(col0 + r0s) * K + c0s;
    const unsigned short* gBhi1 = Bhi + (size_t)(col0 + r1s) * K + c1s;
    const unsigned short* gBlo0 = Blo + (size_t)(col0 + r0s) * K + c0s;
    const unsigned short* gBlo1 = Blo + (size_t)(col0 + r1s) * K + c1s;

    f32x4 acc[2][4];
    const f32x4 zero4 = {0.f, 0.f, 0.f, 0.f};
    #pragma unroll
    for (int i = 0; i < 2; ++i)
        #pragma unroll
        for (int j = 0; j < 4; ++j) acc[i][j] = zero4;

    for (int k0 = 0; k0 < K; k0 += 64) {
        gl_lds16(gA + k0,          sA + (w << 10));
        gl_lds16(gA + k0 + 32,     sA + 4096 + (w << 10));
        gl_lds16(gBhi0 + k0,       sBhi + (w << 10));
        gl_lds16(gBhi1 + k0,       sBhi + 4096 + (w << 10));
        gl_lds16(gBhi0 + k0 + 32,  sBhi + 8192 + (w << 10));
        gl_lds16(gBhi1 + k0 + 32,  sBhi + 12288 + (w << 10));
        gl_lds16(gBlo0 + k0,       sBlo + (w << 10));
        gl_lds16(gBlo1 + k0,       sBlo + 4096 + (w << 10));
        gl_lds16(gBlo0 + k0 + 32,  sBlo + 8192 + (w << 10));
        gl_lds16(gBlo1 + k0 + 32,  sBlo + 12288 + (w << 10));
        __syncthreads();
        #pragma unroll
        for (int h = 0; h < 2; ++h) {
            const int ao = h * 4096, bo = h * 8192;
            bf16x8 ah[2], bh[4], bl[4];
            #pragma unroll
            for (int i = 0; i < 2; ++i) ah[i] = *(const bf16x8*)(sA + ao + aoff[i]);
            #pragma unroll
            for (int j = 0; j < 4; ++j) {
                bh[j] = *(const bf16x8*)(sBhi + bo + boff[j]);
                bl[j] = *(const bf16x8*)(sBlo + bo + boff[j]);
            }
            #pragma unroll
            for (int mi = 0; mi < 2; ++mi)
                #pragma unroll
                for (int ni = 0; ni < 4; ++ni) {
                    acc[mi][ni] = __builtin_amdgcn_mfma_f32_16x16x32_bf16(ah[mi], bh[ni], acc[mi][ni], 0, 0, 0);
                    acc[mi][ni] = __builtin_amdgcn_mfma_f32_16x16x32_bf16(ah[mi], bl[ni], acc[mi][ni], 0, 0, 0);
                }
        }
        __syncthreads();
    }

    int cc[4]; float bv[4];
    #pragma unroll
    for (int ni = 0; ni < 4; ++ni) {
        cc[ni] = col0 + wc * 64 + ni * 16 + r16;
        bv[ni] = bias[cc[ni]];
    }
    if (MODE == 0) {
        unsigned short* CE = Cout + (size_t)e * M * N;
        #pragma unroll
        for (int mi = 0; mi < 2; ++mi) {
            int rb = row0 + wr * 32 + mi * 16 + quad * 4;
            #pragma unroll
            for (int reg = 0; reg < 4; ++reg) {
                size_t roff = (size_t)(rb + reg) * N;
                #pragma unroll
                for (int ni = 0; ni < 4; ++ni)
                    CE[roff + cc[ni]] = f2b(gelu_f(acc[mi][ni][reg] + bv[ni]));
            }
        }
    } else {
        #pragma unroll
        for (int mi = 0; mi < 2; ++mi) {
            int rb = row0 + wr * 32 + mi * 16 + quad * 4;
            #pragma unroll
            for (int reg = 0; reg < 4; ++reg) {
                int i = rb + reg;
                if (i < cn) {
                    int tok = listG[e * NTOK + i];
                    float g = gates[(size_t)tok * Ee + e];
                    size_t roff = (size_t)tok * N;
                    #pragma unroll
                    for (int ni = 0; ni < 4; ++ni)
                        atomicAdd(&outf[roff + cc[ni]], g * (acc[mi][ni][reg] + bv[ni]));
                }
            }
        }
    }
}

// ============================ router tail + downsample ==============================

__global__ __launch_bounds__(256) void logits_accum(const float* __restrict__ h,
                                                    const float* __restrict__ fl_w,
                                                    float* __restrict__ logits) {
    int b = blockIdx.x;
    int chunk = blockIdx.y;
    __shared__ float wsm[Ee][128];
    for (int i = threadIdx.x; i < Ee * 128; i += 256) {
        int e = i >> 7, l = i & 127;
        wsm[e][l] = fl_w[e * Ll + chunk * 128 + l];
    }
    __syncthreads();
    int d = threadIdx.x;
    float acc[Ee] = {};
    for (int l = 0; l < 128; ++l) {
        float v = h[((size_t)b * Ll + chunk * 128 + l) * Dd + d];
        #pragma unroll
        for (int e = 0; e < Ee; ++e) acc[e] += v * wsm[e][l];
    }
    int tok = b * Dd + d;
    #pragma unroll
    for (int e = 0; e < Ee; ++e) atomicAdd(&logits[tok * Ee + e], acc[e]);
}

// sigmoid -> softmax -> top2 -> gates + per-expert lists + balanced tile table.
// ONE block of 1024 threads (2 toks each) so cnt is final before table build.
__global__ __launch_bounds__(1024) void gates_final(const float* __restrict__ logits,
                                                    const float* __restrict__ fl_b,
                                                    float* __restrict__ gates,
                                                    int* __restrict__ cnt,
                                                    int* __restrict__ list,
                                                    int* __restrict__ tileTab,
                                                    int* __restrict__ ntiles) {
    for (int tok = threadIdx.x; tok < NTOK; tok += 1024) {
        float s[Ee];
        #pragma unroll
        for (int e = 0; e < Ee; ++e) {
            float z = logits[tok * Ee + e] + fl_b[e];
            s[e] = 1.0f / (1.0f + expf(-z));
        }
        float mx = s[0];
        #pragma unroll
        for (int e = 1; e < Ee; ++e) mx = fmaxf(mx, s[e]);
        float p[Ee];
        #pragma unroll
        for (int e = 0; e < Ee; ++e) p[e] = expf(s[e] - mx);
        int i1 = 0;
        #pragma unroll
        for (int e = 1; e < Ee; ++e) if (p[e] > p[i1]) i1 = e;
        int i2 = (i1 == 0) ? 1 : 0;
        #pragma unroll
        for (int e = 0; e < Ee; ++e) {
            if (e == i1 || e == i2) continue;
            if (p[e] > p[i2]) i2 = e;
        }
        float inv = 1.0f / (p[i1] + p[i2]);
        #pragma unroll
        for (int e = 0; e < Ee; ++e) gates[tok * Ee + e] = 0.0f;
        gates[tok * Ee + i1] = p[i1] * inv;
        gates[tok * Ee + i2] = p[i2] * inv;
        int p1 = atomicAdd(&cnt[i1], 1);
        list[i1 * NTOK + p1] = tok;
        int p2 = atomicAdd(&cnt[i2], 1);
        list[i2 * NTOK + p2] = tok;
    }
    __syncthreads();
    if (threadIdx.x == 0) {
        int nt = 0;
        for (int e = 0; e < Ee; ++e) {
            int c = atomicAdd(&cnt[e], 0);        // coherent read (atomics bypass L1)
            for (int m = 0; m * 64 < c; ++m) tileTab[nt++] = (e << 16) | m;
        }
        ntiles[0] = nt;
    }
}

// downsample v3: single bf16 plane, valid region only (xe pad cols hit zero
// w1 cols). 8 j/thread, r-outer for load ILP; early-exit past Li.
__global__ __launch_bounds__(256) void downsample_v3(const float* __restrict__ x,
                                                     unsigned short* __restrict__ xe) {
    int e = blockIdx.z;
    int f = e + 2;
    int Li = Ll / f;
    int j0 = blockIdx.x * 8;
    if (j0 >= Li) return;
    int b = blockIdx.y;
    int d = threadIdx.x;
    float invf = 1.0f / (float)f;
    int lim = Li - 1;
    float v[8] = {};
    for (int r = 0; r < f; ++r) {
        #pragma unroll
        for (int jj = 0; jj < 8; ++jj) {
            int j = j0 + jj; if (j > lim) j = lim;
            v[jj] += x[((size_t)(b * Ll + j * f + r)) * Dd + d];
        }
    }
    size_t obase = ((size_t)(e * NTOK + b * 256 + d)) * LMAXc + j0;
    if (j0 + 8 <= Li) {
        u16x8 hv;
        #pragma unroll
        for (int q = 0; q < 8; ++q) hv[q] = (short)f2b(v[q] * invf);
        *(u16x8*)(xe + obase) = hv;
    } else {
        for (int jj = 0; jj < Li - j0; ++jj)
            xe[obase + jj] = f2b(v[jj] * invf);
    }
}

__global__ __launch_bounds__(256) void transpose_out(const float* __restrict__ outacc,
                                                     float* __restrict__ out) {
    __shared__ float tile[32][33];
    int b = blockIdx.z;
    int d0 = blockIdx.x * 32;
    int o0 = blockIdx.y * 32;
    int tx = threadIdx.x & 31, ty = threadIdx.x >> 5;
    for (int i = 0; i < 32; i += 8)
        tile[ty + i][tx] = outacc[((size_t)b * Dd + d0 + ty + i) * Hh + o0 + tx];
    __syncthreads();
    for (int i = 0; i < 32; i += 8)
        out[((size_t)b * Hh + o0 + ty + i) * Dd + d0 + tx] = tile[tx][ty + i];
}

extern "C" void kernel_launch(void* const* d_in, const int* in_sizes, int n_in,
                              void* d_out, int out_size, void* d_ws, size_t ws_size,
                              hipStream_t stream) {
    const float* x       = (const float*)d_in[0];
    const float* conv_w  = (const float*)d_in[1];
    const float* conv_b  = (const float*)d_in[2];
    const float* fl_w    = (const float*)d_in[3];
    const float* fl_b    = (const float*)d_in[4];
    const float* w1      = (const float*)d_in[5];
    const float* b1      = (const float*)d_in[6];
    const float* w2      = (const float*)d_in[7];
    const float* b2      = (const float*)d_in[8];
    const float* w3      = (const float*)d_in[9];
    const float* b3      = (const float*)d_in[10];
    float* out = (float*)d_out;

    char* ws = (char*)d_ws;
    // Workspace (peak ~151.2 MB, proven). Layout identical to R7/R8.
    unsigned short* xphi = (unsigned short*)(ws);
    unsigned short* xplo = (unsigned short*)(ws + 4227072);
    unsigned short* cphi = (unsigned short*)(ws + 8454144);
    unsigned short* cplo = (unsigned short*)(ws + 12681216);
    unsigned short* wchi = (unsigned short*)(ws + 16908288);
    unsigned short* wclo = (unsigned short*)(ws + 18087936);
    float* hL            = (float*)(ws + 19267584);
    unsigned short* h1   = (unsigned short*)(ws);
    unsigned short* h2   = (unsigned short*)(ws + 33554432);
    unsigned short* xe   = (unsigned short*)(ws + 67108864);
    unsigned short* w3hi = (unsigned short*)(ws + 67108864);
    unsigned short* w3lo = (unsigned short*)(ws + 83886080);
    unsigned short* w1hi = (unsigned short*)(ws + 100663296);
    unsigned short* w1lo = (unsigned short*)(ws + 109051904);
    unsigned short* w2hi = (unsigned short*)(ws + 117440512);
    unsigned short* w2lo = (unsigned short*)(ws + 134217728);
    float* logits  = (float*)(ws + 150994944);
    int*   cnt     = (int*)(ws + 151060480);
    int*   ntiles  = (int*)(ws + 151060512);
    int*   tileTab = (int*)(ws + 151060544);
    float* gates   = (float*)(ws + 151061504);
    int*   list    = (int*)(ws + 151127040);
    float* outacc  = (float*)(ws);

    // zero: padded conv buffers (pad rows), and logits+cnt+ntiles in one shot
    hipMemsetAsync(ws, 0, 16908288, stream);
    hipMemsetAsync(logits, 0, 65536 + 64, stream);

    prep_all<<<16640, 256, 0, stream>>>(x, conv_w, w1, w2,
                                        xphi, xplo, wchi, wclo,
                                        w1hi, w1lo, w2hi, w2lo);

    // Router convs on MFMA (3-pass split — ~1e-7 relative, safe for discrete top-2)
    const int WL = 3 * Dd * Dd;
    conv_mfma<0><<<dim3(Bb * Ll / 64, Dd / 64), 256, 0, stream>>>(
        xphi, xplo, wchi + 0 * WL, wclo + 0 * WL, conv_b + 0 * Dd, cphi, cplo, nullptr, 1);
    conv_mfma<0><<<dim3(Bb * Ll / 64, Dd / 64), 256, 0, stream>>>(
        cphi, cplo, wchi + 1 * WL, wclo + 1 * WL, conv_b + 1 * Dd, xphi, xplo, nullptr, 2);
    conv_mfma<1><<<dim3(Bb * Ll / 64, Dd / 64), 256, 0, stream>>>(
        xphi, xplo, wchi + 2 * WL, wclo + 2 * WL, conv_b + 2 * Dd, nullptr, nullptr, hL, 4);

    logits_accum<<<dim3(Bb, 8), 256, 0, stream>>>(hL, fl_w, logits);
    gates_final<<<1, 1024, 0, stream>>>(logits, fl_b, gates, cnt, list, tileTab, ntiles);

    downsample_v3<<<dim3(64, Bb, Ee), 256, 0, stream>>>(x, xe);

    // GEMM1 sparse (gathered A from xe, K=512): h1 compact over dead conv region
    gemm_sp<0, 1><<<dim3(Hh / 128, MAXTILES), 256, 0, stream>>>(
        xe, w1hi, w1lo, b1, nullptr, cnt, list, tileTab, ntiles, h1, nullptr, NTOK, Hh, LMAXc);

    // xe dead: split w3 into its slot
    split_w4<<<8192, 256, 0, stream>>>(w3, w3hi, w3lo, Ee * Hh * Hh / 4);

    // GEMM2 sparse (compact->compact, K=1024)
    gemm_sp<0, 0><<<dim3(Hh / 128, MAXTILES), 256, 0, stream>>>(
        h1, w2hi, w2lo, b2, nullptr, cnt, list, tileTab, ntiles, h2, nullptr, NTOK, Hh, Hh);

    // h1 dead: zero outacc in its slot
    hipMemsetAsync(outacc, 0, (size_t)NTOK * Hh * sizeof(float), stream);

    // GEMM3 sparse (compact A, gated scatter-add combine)
    gemm_sp<1, 0><<<dim3(Hh / 128, MAXTILES), 256, 0, stream>>>(
        h2, w3hi, w3lo, b3, gates, cnt, list, tileTab, ntiles, nullptr, outacc, NTOK, Hh, Hh);

    transpose_out<<<dim3(Dd / 32, Hh / 32, Bb), 256, 0, stream>>>(outacc, out);
}